// Round 2
// baseline (3132.842 us; speedup 1.0000x reference)
//
#include <hip/hip_runtime.h>

#define R_REL 10
#define HD 64   // hidden dim, fixed by problem

// ---------------- histogram of (dst,rel) keys ----------------
__global__ void hist_kernel(const int* __restrict__ dst, const int* __restrict__ et,
                            int* __restrict__ keycnt, int E) {
    int e = blockIdx.x * 256 + threadIdx.x;
    if (e < E) atomicAdd(&keycnt[dst[e] * R_REL + et[e]], 1);
}

// ---------------- 3-kernel exclusive scan over M=N*R ints ----------------
__global__ void scan1_kernel(const int* __restrict__ cnt, int* __restrict__ bsum, int M) {
    int b = blockIdx.x, tid = threadIdx.x;
    int base = b * 1024 + tid * 4;
    int s = 0;
#pragma unroll
    for (int j = 0; j < 4; ++j) { int i = base + j; if (i < M) s += cnt[i]; }
    for (int off = 32; off > 0; off >>= 1) s += __shfl_down(s, off);
    __shared__ int wsum[4];
    int lane = tid & 63, wid = tid >> 6;
    if (lane == 0) wsum[wid] = s;
    __syncthreads();
    if (tid == 0) bsum[b] = wsum[0] + wsum[1] + wsum[2] + wsum[3];
}

__global__ void scan2_kernel(const int* __restrict__ bsum, int* __restrict__ boff, int NB) {
    int tid = threadIdx.x;           // 1024 threads
    int lane = tid & 63, wid = tid >> 6;
    int v = (tid < NB) ? bsum[tid] : 0;
    int x = v;
    for (int off = 1; off < 64; off <<= 1) { int u = __shfl_up(x, off); if (lane >= off) x += u; }
    __shared__ int wsum[16];
    if (lane == 63) wsum[wid] = x;
    __syncthreads();
    int woff = 0;
    for (int w = 0; w < wid; ++w) woff += wsum[w];
    if (tid < NB) boff[tid] = x + woff - v;   // exclusive
}

__global__ void scan3_kernel(const int* __restrict__ cnt, const int* __restrict__ boff,
                             int* __restrict__ rowptr, int* __restrict__ cursor, int M) {
    int b = blockIdx.x, tid = threadIdx.x;
    int base = b * 1024 + tid * 4;
    int c[4]; int s = 0;
#pragma unroll
    for (int j = 0; j < 4; ++j) { int i = base + j; c[j] = (i < M) ? cnt[i] : 0; s += c[j]; }
    int lane = tid & 63, wid = tid >> 6;
    int x = s;
    for (int off = 1; off < 64; off <<= 1) { int u = __shfl_up(x, off); if (lane >= off) x += u; }
    __shared__ int wsum[4];
    if (lane == 63) wsum[wid] = x;
    __syncthreads();
    int woff = 0;
    for (int w = 0; w < wid; ++w) woff += wsum[w];
    int run = boff[b] + x + woff - s;        // exclusive start for this thread
#pragma unroll
    for (int j = 0; j < 4; ++j) {
        int i = base + j;
        if (i < M) {
            rowptr[i] = run; cursor[i] = run; run += c[j];
            if (i == M - 1) rowptr[M] = run;
        }
    }
}

// in-place: read int count, write float 1/max(cnt,1) into same buffer
__global__ void inv_kernel(int* __restrict__ cnt, int M) {
    int i = blockIdx.x * 256 + threadIdx.x;
    if (i < M) {
        float c = (float)cnt[i];
        ((float*)cnt)[i] = 1.0f / fmaxf(c, 1.0f);
    }
}

__global__ void fill_kernel(const int* __restrict__ src, const int* __restrict__ dst,
                            const int* __restrict__ et, int* __restrict__ cursor,
                            int* __restrict__ elist, int E) {
    int e = blockIdx.x * 256 + threadIdx.x;
    if (e < E) {
        int key = dst[e] * R_REL + et[e];
        int slot = atomicAdd(&cursor[key], 1);
        elist[slot] = src[e];
    }
}

// ---------------- tiled f32 GEMM: Y = X @ W  (X: [N,K], W: [K,64], Y: [N,64]) ----
// block: 256 thr, 64-node tile x 64 outs; micro 4 nodes x 4 outs; k-unroll 4.
template <int K>
__global__ __launch_bounds__(256) void gemm_kernel(const float* __restrict__ X,
                                                   const float* __restrict__ W,
                                                   float* __restrict__ Y, int N) {
    __shared__ float xs[64][K + 4];   // K=128: 33.8 KB; K=64: 17.4 KB
    __shared__ float wsm[64][HD];     // 16 KB: 64 k-rows staged at a time
    const int tid = threadIdx.x;
    const int tx = tid & 15, ty = tid >> 4;
    const int n0 = blockIdx.x * 64;
    constexpr int NF = K / 4;
    for (int idx = tid; idx < 64 * NF; idx += 256) {
        int n = idx / NF, k4 = (idx % NF) * 4;
        int node = n0 + n;
        float4 v = make_float4(0.f, 0.f, 0.f, 0.f);
        if (node < N) v = *(const float4*)(X + (size_t)node * K + k4);
        *(float4*)&xs[n][k4] = v;
    }
    float4 acc[4];
#pragma unroll
    for (int i = 0; i < 4; ++i) acc[i] = make_float4(0.f, 0.f, 0.f, 0.f);
    for (int kb = 0; kb < K; kb += 64) {
        __syncthreads();   // xs staging done (first pass) / wsm readers done (later passes)
        for (int idx = tid; idx < 64 * 16; idx += 256) {
            int k = idx >> 4, h4 = (idx & 15) * 4;
            *(float4*)&wsm[k][h4] = *(const float4*)(W + (size_t)(kb + k) * HD + h4);
        }
        __syncthreads();
#pragma unroll
        for (int kk = 0; kk < 64; kk += 4) {
            float4 w0 = *(const float4*)&wsm[kk + 0][tx * 4];
            float4 w1 = *(const float4*)&wsm[kk + 1][tx * 4];
            float4 w2 = *(const float4*)&wsm[kk + 2][tx * 4];
            float4 w3 = *(const float4*)&wsm[kk + 3][tx * 4];
#pragma unroll
            for (int i = 0; i < 4; ++i) {
                float4 xv = *(const float4*)&xs[ty + 16 * i][kb + kk];
                acc[i].x += xv.x * w0.x + xv.y * w1.x + xv.z * w2.x + xv.w * w3.x;
                acc[i].y += xv.x * w0.y + xv.y * w1.y + xv.z * w2.y + xv.w * w3.y;
                acc[i].z += xv.x * w0.z + xv.y * w1.z + xv.z * w2.z + xv.w * w3.z;
                acc[i].w += xv.x * w0.w + xv.y * w1.w + xv.z * w2.w + xv.w * w3.w;
            }
        }
    }
#pragma unroll
    for (int i = 0; i < 4; ++i) {
        int node = n0 + ty + 16 * i;
        if (node < N) *(float4*)(Y + (size_t)node * HD + tx * 4) = acc[i];
    }
}

// ---------------- per-relation aggregation: one wave per dst node, no atomics ----
__global__ __launch_bounds__(256) void agg_rel_kernel(const float* __restrict__ h_r,
                                                      const int* __restrict__ rowptr,
                                                      const int* __restrict__ elist,
                                                      const float* __restrict__ inv,
                                                      float* __restrict__ acc,
                                                      int N, int rel) {
    int gid = blockIdx.x * 256 + threadIdx.x;
    int d = gid >> 6;
    int lane = threadIdx.x & 63;
    if (d >= N) return;
    int key = d * R_REL + rel;
    int s0 = rowptr[key], s1 = rowptr[key + 1];
    if (s1 == s0) return;
    float sum = 0.f;
    for (int i = s0; i < s1; ++i) {
        int s = elist[i];
        sum += h_r[(size_t)s * HD + lane];
    }
    acc[(size_t)d * HD + lane] += sum * inv[key];
}

// ---------------- finalize: out = relu(acc + bias) ----------------
__global__ __launch_bounds__(256) void finalize_kernel(const float* __restrict__ acc,
                                                       const float* __restrict__ bias,
                                                       float* __restrict__ out, int NH) {
    int i = blockIdx.x * 256 + threadIdx.x;
    if (i < NH) out[i] = fmaxf(acc[i] + bias[i & (HD - 1)], 0.f);
}

// ---------------- mean pool (batch is sorted -> block pre-reduction) ----------------
__global__ __launch_bounds__(256) void pool_kernel(const float* __restrict__ h,
                                                   const int* __restrict__ batch,
                                                   float* __restrict__ pooled,
                                                   float* __restrict__ gcnt, int N) {
    __shared__ float part[64];
    __shared__ int gs[4];
    int tid = threadIdx.x;
    int nl = tid >> 6, j = tid & 63;
    int n = blockIdx.x * 4 + nl;
    bool valid = n < N;
    int g = valid ? batch[n] : -1;
    if (j == 0) gs[nl] = g;
    if (tid < 64) part[j] = 0.f;
    __syncthreads();
    bool uni = (gs[0] >= 0) && (gs[0] == gs[1]) && (gs[1] == gs[2]) && (gs[2] == gs[3]);
    float val = valid ? h[(size_t)n * HD + j] : 0.f;
    if (uni) {
        atomicAdd(&part[j], val);
        __syncthreads();
        if (nl == 0) atomicAdd(&pooled[g * 64 + j], part[j]);
        if (tid == 0) atomicAdd(gcnt + g, 4.0f);
    } else {
        if (valid) {
            atomicAdd(&pooled[g * 64 + j], val);
            if (j == 0) atomicAdd(gcnt + g, 1.0f);
        }
    }
}

__global__ void cls_kernel(const float* __restrict__ pooled, const float* __restrict__ gcnt,
                           const float* __restrict__ cls_w, const float* __restrict__ cls_b,
                           float* __restrict__ out) {
    int g = threadIdx.x;   // 64 graphs
    float invc = 1.0f / fmaxf(gcnt[g], 1.0f);
    float acc = 0.f;
    for (int j = 0; j < 64; ++j) acc += pooled[g * 64 + j] * cls_w[j];
    out[g] = acc * invc + cls_b[0];
}

extern "C" void kernel_launch(void* const* d_in, const int* in_sizes, int n_in,
                              void* d_out, int out_size, void* d_ws, size_t ws_size,
                              hipStream_t stream) {
    const float* x     = (const float*)d_in[0];
    const int*   eidx  = (const int*)d_in[1];
    const int*   et    = (const int*)d_in[2];
    const int*   batch = (const int*)d_in[3];
    const float* W1    = (const float*)d_in[4];
    const float* root1 = (const float*)d_in[5];
    const float* b1    = (const float*)d_in[6];
    const float* W2    = (const float*)d_in[7];
    const float* root2 = (const float*)d_in[8];
    const float* b2    = (const float*)d_in[9];
    const float* cls_w = (const float*)d_in[10];
    const float* cls_b = (const float*)d_in[11];

    const int N = in_sizes[3];
    const int E = in_sizes[2];
    const int M = N * R_REL;
    const int NB = (M + 1023) / 1024;
    const int* srcp = eidx;
    const int* dstp = eidx + E;

    char* ws = (char*)d_ws;
    size_t off = 0;
    auto alloc = [&](size_t bytes) -> void* {
        void* p = ws + off;
        off = (off + bytes + 255) & ~(size_t)255;
        return p;
    };
    // total ~102 MB
    float* h_r      = (float*)alloc((size_t)N * HD * 4);           // 25.6 MB per-relation transform
    float* accb     = (float*)alloc((size_t)N * HD * 4);           // 25.6 MB layer accumulator
    float* h1       = (float*)alloc((size_t)N * HD * 4);           // 25.6 MB layer-1 output
    int*   keycnt   = (int*)alloc((size_t)M * 4);                  // counts, then in-place inv float
    int*   rowptr   = (int*)alloc((size_t)(M + 1) * 4);
    int*   cursor   = (int*)alloc((size_t)M * 4);
    int*   elist    = (int*)alloc((size_t)E * 4);                  // 12.8 MB
    int*   bsum     = (int*)alloc((size_t)NB * 4);
    int*   boff     = (int*)alloc((size_t)NB * 4);
    float* pooled   = (float*)alloc((size_t)(64 * 64 + 64) * 4);
    float* gcnt     = pooled + 64 * 64;
    float* invf     = (float*)keycnt;   // after inv_kernel, keycnt holds floats

    hipMemsetAsync(keycnt, 0, (size_t)M * 4, stream);
    hipMemsetAsync(pooled, 0, (size_t)(64 * 64 + 64) * 4, stream);

    // ---- build CSR over (dst,rel) keys ----
    hist_kernel<<<(E + 255) / 256, 256, 0, stream>>>(dstp, et, keycnt, E);
    scan1_kernel<<<NB, 256, 0, stream>>>(keycnt, bsum, M);
    scan2_kernel<<<1, 1024, 0, stream>>>(bsum, boff, NB);
    scan3_kernel<<<NB, 256, 0, stream>>>(keycnt, boff, rowptr, cursor, M);
    fill_kernel<<<(E + 255) / 256, 256, 0, stream>>>(srcp, dstp, et, cursor, elist, E);
    inv_kernel<<<(M + 255) / 256, 256, 0, stream>>>(keycnt, M);   // in-place int->float

    const int gemmBlocks = (N + 63) / 64;
    const int aggBlocks  = (int)(((size_t)N * 64 + 255) / 256);
    const int NH = N * HD;
    const int finBlocks = (NH + 255) / 256;

    // ---- layer 1 (K=128) ----
    gemm_kernel<128><<<gemmBlocks, 256, 0, stream>>>(x, root1, accb, N);   // acc = x @ root1
    for (int r = 0; r < R_REL; ++r) {
        gemm_kernel<128><<<gemmBlocks, 256, 0, stream>>>(x, W1 + (size_t)r * 128 * HD, h_r, N);
        agg_rel_kernel<<<aggBlocks, 256, 0, stream>>>(h_r, rowptr, elist, invf, accb, N, r);
    }
    finalize_kernel<<<finBlocks, 256, 0, stream>>>(accb, b1, h1, NH);      // h1 = relu(acc + b1)

    // ---- layer 2 (K=64) ----
    gemm_kernel<64><<<gemmBlocks, 256, 0, stream>>>(h1, root2, accb, N);   // acc = h1 @ root2
    for (int r = 0; r < R_REL; ++r) {
        gemm_kernel<64><<<gemmBlocks, 256, 0, stream>>>(h1, W2 + (size_t)r * 64 * HD, h_r, N);
        agg_rel_kernel<<<aggBlocks, 256, 0, stream>>>(h_r, rowptr, elist, invf, accb, N, r);
    }
    finalize_kernel<<<finBlocks, 256, 0, stream>>>(accb, b2, accb, NH);    // in-place relu+bias

    // ---- pool + classify ----
    pool_kernel<<<(N + 3) / 4, 256, 0, stream>>>(accb, batch, pooled, gcnt, N);
    cls_kernel<<<1, 64, 0, stream>>>(pooled, gcnt, cls_w, cls_b, (float*)d_out);
}

// Round 3
// 1404.429 us; speedup vs baseline: 2.2307x; 2.2307x over previous
//
#include <hip/hip_runtime.h>

#define R_REL 10
#define HD 64   // hidden dim, fixed by problem

typedef __attribute__((ext_vector_type(8))) short short8;
typedef __attribute__((ext_vector_type(4))) float floatx4;
typedef __attribute__((ext_vector_type(8))) unsigned short ushort8;

__device__ inline unsigned short f32_to_bf16_rne(float f) {
    unsigned int u = __float_as_uint(f);
    unsigned int r = (u + 0x7FFFu + ((u >> 16) & 1u)) >> 16;
    return (unsigned short)r;
}
__device__ inline float bf16_to_f32(unsigned short h) {
    return __uint_as_float(((unsigned int)h) << 16);
}

// ---------------- histogram of (dst,rel) keys ----------------
__global__ void hist_kernel(const int* __restrict__ dst, const int* __restrict__ et,
                            int* __restrict__ keycnt, int E) {
    int e = blockIdx.x * 256 + threadIdx.x;
    if (e < E) atomicAdd(&keycnt[dst[e] * R_REL + et[e]], 1);
}

// ---------------- 3-kernel exclusive scan over M=N*R ints ----------------
__global__ void scan1_kernel(const int* __restrict__ cnt, int* __restrict__ bsum, int M) {
    int b = blockIdx.x, tid = threadIdx.x;
    int base = b * 1024 + tid * 4;
    int s = 0;
#pragma unroll
    for (int j = 0; j < 4; ++j) { int i = base + j; if (i < M) s += cnt[i]; }
    for (int off = 32; off > 0; off >>= 1) s += __shfl_down(s, off);
    __shared__ int wsum[4];
    int lane = tid & 63, wid = tid >> 6;
    if (lane == 0) wsum[wid] = s;
    __syncthreads();
    if (tid == 0) bsum[b] = wsum[0] + wsum[1] + wsum[2] + wsum[3];
}

__global__ void scan2_kernel(const int* __restrict__ bsum, int* __restrict__ boff, int NB) {
    int tid = threadIdx.x;           // 1024 threads
    int lane = tid & 63, wid = tid >> 6;
    int v = (tid < NB) ? bsum[tid] : 0;
    int x = v;
    for (int off = 1; off < 64; off <<= 1) { int u = __shfl_up(x, off); if (lane >= off) x += u; }
    __shared__ int wsum[16];
    if (lane == 63) wsum[wid] = x;
    __syncthreads();
    int woff = 0;
    for (int w = 0; w < wid; ++w) woff += wsum[w];
    if (tid < NB) boff[tid] = x + woff - v;   // exclusive
}

__global__ void scan3_kernel(const int* __restrict__ cnt, const int* __restrict__ boff,
                             int* __restrict__ rowptr, int* __restrict__ cursor, int M) {
    int b = blockIdx.x, tid = threadIdx.x;
    int base = b * 1024 + tid * 4;
    int c[4]; int s = 0;
#pragma unroll
    for (int j = 0; j < 4; ++j) { int i = base + j; c[j] = (i < M) ? cnt[i] : 0; s += c[j]; }
    int lane = tid & 63, wid = tid >> 6;
    int x = s;
    for (int off = 1; off < 64; off <<= 1) { int u = __shfl_up(x, off); if (lane >= off) x += u; }
    __shared__ int wsum[4];
    if (lane == 63) wsum[wid] = x;
    __syncthreads();
    int woff = 0;
    for (int w = 0; w < wid; ++w) woff += wsum[w];
    int run = boff[b] + x + woff - s;        // exclusive start for this thread
#pragma unroll
    for (int j = 0; j < 4; ++j) {
        int i = base + j;
        if (i < M) {
            rowptr[i] = run; cursor[i] = run; run += c[j];
            if (i == M - 1) rowptr[M] = run;
        }
    }
}

// in-place: read int count, write float 1/max(cnt,1) into same buffer
__global__ void inv_kernel(int* __restrict__ cnt, int M) {
    int i = blockIdx.x * 256 + threadIdx.x;
    if (i < M) {
        float c = (float)cnt[i];
        ((float*)cnt)[i] = 1.0f / fmaxf(c, 1.0f);
    }
}

__global__ void fill_kernel(const int* __restrict__ src, const int* __restrict__ dst,
                            const int* __restrict__ et, int* __restrict__ cursor,
                            int* __restrict__ elist, int E) {
    int e = blockIdx.x * 256 + threadIdx.x;
    if (e < E) {
        int key = dst[e] * R_REL + et[e];
        int slot = atomicAdd(&cursor[key], 1);
        elist[slot] = src[e];
    }
}

// ---------------- hi/lo bf16 split of a f32 array ----------------
__global__ void split_kernel(const float* __restrict__ src, unsigned short* __restrict__ hi,
                             unsigned short* __restrict__ lo, int n) {
    int i = blockIdx.x * 256 + threadIdx.x;
    if (i < n) {
        float v = src[i];
        unsigned short h = f32_to_bf16_rne(v);
        hi[i] = h;
        lo[i] = f32_to_bf16_rne(v - bf16_to_f32(h));
    }
}

// W [R][K][HD] + root [K][HD] f32  ->  Wt hi/lo bf16 [(R+1)][HD][K]  (n-major, k contiguous)
__global__ void wsplit_kernel(const float* __restrict__ W, const float* __restrict__ root,
                              unsigned short* __restrict__ hi, unsigned short* __restrict__ lo,
                              int K) {
    int idx = blockIdx.x * 256 + threadIdx.x;
    int total = (R_REL + 1) * HD * K;
    if (idx >= total) return;
    int rel = idx / (HD * K);
    int rem = idx - rel * HD * K;
    int n = rem / K, k = rem - n * K;
    float v = (rel < R_REL) ? W[((size_t)rel * K + k) * HD + n] : root[(size_t)k * HD + n];
    unsigned short h = f32_to_bf16_rne(v);
    hi[idx] = h;
    lo[idx] = f32_to_bf16_rne(v - bf16_to_f32(h));
}

// ---------------- MFMA GEMM: per block 64 nodes x 64 outs, nrel relations ----
// 3-term bf16 split (ah*bh + al*bh + ah*bl) ~ f32 accuracy.
// wave w computes out cols [w*16, w*16+16) for all 64 nodes (4 M-tiles).
// A frags from LDS (X tile, +8 bf16 pad), B frags direct global (Wt is n-major).
template <int K, bool F32OUT>
__global__ __launch_bounds__(256) void gemm_mfma(const unsigned short* __restrict__ Xhi,
                                                 const unsigned short* __restrict__ Xlo,
                                                 const unsigned short* __restrict__ Wthi,
                                                 const unsigned short* __restrict__ Wtlo,
                                                 unsigned short* __restrict__ hout,
                                                 float* __restrict__ fout,
                                                 int r0, int nrel, int N) {
    constexpr int LDK = K + 8;
    __shared__ unsigned short xs_hi[64 * LDK];
    __shared__ unsigned short xs_lo[64 * LDK];
    const int tid = threadIdx.x;
    const int w = tid >> 6, lane = tid & 63;
    const int n0 = blockIdx.x * 64;
    constexpr int CH = K / 8;          // 16B chunks per row
    constexpr int RPI = 256 / CH;      // rows staged per iteration
#pragma unroll
    for (int it = 0; it < 64 / RPI; ++it) {
        int row = it * RPI + tid / CH;
        int ck = (tid & (CH - 1)) * 8;
        int node = n0 + row;
        ushort8 vh, vl;
#pragma unroll
        for (int q = 0; q < 8; ++q) { vh[q] = 0; vl[q] = 0; }
        if (node < N) {
            vh = *(const ushort8*)(Xhi + (size_t)node * K + ck);
            vl = *(const ushort8*)(Xlo + (size_t)node * K + ck);
        }
        *(ushort8*)&xs_hi[row * LDK + ck] = vh;
        *(ushort8*)&xs_lo[row * LDK + ck] = vl;
    }
    __syncthreads();
    const int quad = lane >> 4, l16 = lane & 15;
    const int colg = w * 16 + l16;
    for (int c = 0; c < nrel; ++c) {
        int rel = r0 + c;
        const unsigned short* bh_base = Wthi + ((size_t)rel * HD + colg) * K + quad * 8;
        const unsigned short* bl_base = Wtlo + ((size_t)rel * HD + colg) * K + quad * 8;
        floatx4 zero = {0.f, 0.f, 0.f, 0.f};
        floatx4 acc[4];
#pragma unroll
        for (int mt = 0; mt < 4; ++mt) acc[mt] = zero;
#pragma unroll
        for (int s = 0; s < K / 32; ++s) {
            short8 bh = *(const short8*)(bh_base + s * 32);
            short8 bl = *(const short8*)(bl_base + s * 32);
            int ko = s * 32 + quad * 8;
#pragma unroll
            for (int mt = 0; mt < 4; ++mt) {
                short8 ah = *(const short8*)&xs_hi[(mt * 16 + l16) * LDK + ko];
                short8 al = *(const short8*)&xs_lo[(mt * 16 + l16) * LDK + ko];
                acc[mt] = __builtin_amdgcn_mfma_f32_16x16x32_bf16(ah, bh, acc[mt], 0, 0, 0);
                acc[mt] = __builtin_amdgcn_mfma_f32_16x16x32_bf16(al, bh, acc[mt], 0, 0, 0);
                acc[mt] = __builtin_amdgcn_mfma_f32_16x16x32_bf16(ah, bl, acc[mt], 0, 0, 0);
            }
        }
        // C/D layout: col = lane&15, row = quad*4 + reg  [HW-verified]
#pragma unroll
        for (int mt = 0; mt < 4; ++mt) {
#pragma unroll
            for (int r = 0; r < 4; ++r) {
                int node = n0 + mt * 16 + quad * 4 + r;
                if (node < N) {
                    if (F32OUT)
                        fout[(size_t)node * HD + colg] = acc[mt][r];
                    else
                        hout[(size_t)c * N * HD + (size_t)node * HD + colg] =
                            f32_to_bf16_rne(acc[mt][r]);
                }
            }
        }
    }
}

// ---------------- chunked aggregation: one wave per dst, one acc RMW per chunk ----
__global__ __launch_bounds__(256) void agg_chunk_kernel(const unsigned short* __restrict__ hc,
                                                        const int* __restrict__ rowptr,
                                                        const int* __restrict__ elist,
                                                        const float* __restrict__ inv,
                                                        float* __restrict__ acc,
                                                        int N, int r0, int nrel) {
    int gid = blockIdx.x * 256 + threadIdx.x;
    int d = gid >> 6;
    int lane = threadIdx.x & 63;
    if (d >= N) return;
    float total = 0.f;
    bool any = false;
    for (int c = 0; c < nrel; ++c) {
        int key = d * R_REL + r0 + c;
        int s0 = rowptr[key], s1 = rowptr[key + 1];
        if (s1 > s0) {
            const unsigned short* hb = hc + (size_t)c * N * HD + lane;
            float sum = 0.f;
            for (int i = s0; i < s1; ++i)
                sum += bf16_to_f32(hb[(size_t)elist[i] * HD]);
            total += sum * inv[key];
            any = true;
        }
    }
    if (any) acc[(size_t)d * HD + lane] += total;
}

// ---------------- finalize layer 1: relu(acc+b) -> bf16 hi/lo ----------------
__global__ void fin1_kernel(const float* __restrict__ acc, const float* __restrict__ bias,
                            unsigned short* __restrict__ hi, unsigned short* __restrict__ lo,
                            int NH) {
    int i = blockIdx.x * 256 + threadIdx.x;
    if (i < NH) {
        float v = fmaxf(acc[i] + bias[i & (HD - 1)], 0.f);
        unsigned short h = f32_to_bf16_rne(v);
        hi[i] = h;
        lo[i] = f32_to_bf16_rne(v - bf16_to_f32(h));
    }
}

// ---------------- mean pool, fused relu+bias: wave per 256 sorted nodes -------
__global__ __launch_bounds__(256) void pool_kernel(const float* __restrict__ acc,
                                                   const float* __restrict__ bias,
                                                   const int* __restrict__ batch,
                                                   float* __restrict__ pooled,
                                                   float* __restrict__ gcnt, int N) {
    int w = blockIdx.x * 4 + (threadIdx.x >> 6);
    int lane = threadIdx.x & 63;
    int base = w * 256;
    if (base >= N) return;
    float b = bias[lane];
    int cur = -1; float sum = 0.f; int cnt = 0;
    int end = min(base + 256, N);
    for (int n = base; n < end; ++n) {
        int g = batch[n];
        if (g != cur) {
            if (cur >= 0) {
                atomicAdd(&pooled[cur * HD + lane], sum);
                if (lane == 0) atomicAdd(&gcnt[cur], (float)cnt);
            }
            cur = g; sum = 0.f; cnt = 0;
        }
        sum += fmaxf(acc[(size_t)n * HD + lane] + b, 0.f);
        cnt++;
    }
    if (cur >= 0) {
        atomicAdd(&pooled[cur * HD + lane], sum);
        if (lane == 0) atomicAdd(&gcnt[cur], (float)cnt);
    }
}

__global__ void cls_kernel(const float* __restrict__ pooled, const float* __restrict__ gcnt,
                           const float* __restrict__ cls_w, const float* __restrict__ cls_b,
                           float* __restrict__ out) {
    int g = threadIdx.x;   // 64 graphs
    float invc = 1.0f / fmaxf(gcnt[g], 1.0f);
    float acc = 0.f;
    for (int j = 0; j < 64; ++j) acc += pooled[g * 64 + j] * cls_w[j];
    out[g] = acc * invc + cls_b[0];
}

extern "C" void kernel_launch(void* const* d_in, const int* in_sizes, int n_in,
                              void* d_out, int out_size, void* d_ws, size_t ws_size,
                              hipStream_t stream) {
    const float* x     = (const float*)d_in[0];
    const int*   eidx  = (const int*)d_in[1];
    const int*   et    = (const int*)d_in[2];
    const int*   batch = (const int*)d_in[3];
    const float* W1    = (const float*)d_in[4];
    const float* root1 = (const float*)d_in[5];
    const float* b1    = (const float*)d_in[6];
    const float* W2    = (const float*)d_in[7];
    const float* root2 = (const float*)d_in[8];
    const float* b2    = (const float*)d_in[9];
    const float* cls_w = (const float*)d_in[10];
    const float* cls_b = (const float*)d_in[11];

    const int N = in_sizes[3];
    const int E = in_sizes[2];
    const int M = N * R_REL;
    const int NB = (M + 1023) / 1024;
    const int* srcp = eidx;
    const int* dstp = eidx + E;

    char* ws = (char*)d_ws;
    size_t off = 0;
    auto alloc = [&](size_t bytes) -> void* {
        void* p = ws + off;
        off = (off + bytes + 255) & ~(size_t)255;
        return p;
    };
    // fixed buffers (~128 MB)
    unsigned short* Xhi  = (unsigned short*)alloc((size_t)N * 128 * 2);   // 25.6 MB
    unsigned short* Xlo  = (unsigned short*)alloc((size_t)N * 128 * 2);   // 25.6 MB
    unsigned short* H1hi = (unsigned short*)alloc((size_t)N * HD * 2);    // 12.8 MB
    unsigned short* H1lo = (unsigned short*)alloc((size_t)N * HD * 2);    // 12.8 MB
    float*          accb = (float*)alloc((size_t)N * HD * 4);             // 25.6 MB
    unsigned short* Wt1hi = (unsigned short*)alloc((size_t)(R_REL + 1) * HD * 128 * 2);
    unsigned short* Wt1lo = (unsigned short*)alloc((size_t)(R_REL + 1) * HD * 128 * 2);
    unsigned short* Wt2hi = (unsigned short*)alloc((size_t)(R_REL + 1) * HD * HD * 2);
    unsigned short* Wt2lo = (unsigned short*)alloc((size_t)(R_REL + 1) * HD * HD * 2);
    int*   keycnt = (int*)alloc((size_t)M * 4);
    int*   rowptr = (int*)alloc((size_t)(M + 1) * 4);
    int*   cursor = (int*)alloc((size_t)M * 4);
    int*   elist  = (int*)alloc((size_t)E * 4);                           // 12.8 MB
    int*   bsum   = (int*)alloc((size_t)NB * 4);
    int*   boff   = (int*)alloc((size_t)NB * 4);
    float* pooled = (float*)alloc((size_t)(64 * HD + 64) * 4);
    float* gcnt   = pooled + 64 * HD;
    float* invf   = (float*)keycnt;

    // relation-chunk buffer from whatever workspace remains (12.8 MB per relation)
    size_t per_rel = ((size_t)N * HD * 2 + 255) & ~(size_t)255;
    size_t remain = (ws_size > off) ? (ws_size - off) : 0;
    int C = (int)(remain / per_rel);
    if (C < 1) C = 1;                 // ws_size >= 141 MB assumed (round-2 used 102 MB fine)
    if (C > R_REL) C = R_REL;
    unsigned short* h_chunk = (unsigned short*)alloc((size_t)C * per_rel);

    hipMemsetAsync(keycnt, 0, (size_t)M * 4, stream);
    hipMemsetAsync(pooled, 0, (size_t)(64 * HD + 64) * 4, stream);

    // ---- CSR over (dst,rel) keys ----
    hist_kernel<<<(E + 255) / 256, 256, 0, stream>>>(dstp, et, keycnt, E);
    scan1_kernel<<<NB, 256, 0, stream>>>(keycnt, bsum, M);
    scan2_kernel<<<1, 1024, 0, stream>>>(bsum, boff, NB);
    scan3_kernel<<<NB, 256, 0, stream>>>(keycnt, boff, rowptr, cursor, M);
    fill_kernel<<<(E + 255) / 256, 256, 0, stream>>>(srcp, dstp, et, cursor, elist, E);
    inv_kernel<<<(M + 255) / 256, 256, 0, stream>>>(keycnt, M);

    // ---- precision-split operands ----
    int NK = N * 128;
    split_kernel<<<(NK + 255) / 256, 256, 0, stream>>>(x, Xhi, Xlo, NK);
    int tw1 = (R_REL + 1) * HD * 128, tw2 = (R_REL + 1) * HD * HD;
    wsplit_kernel<<<(tw1 + 255) / 256, 256, 0, stream>>>(W1, root1, Wt1hi, Wt1lo, 128);
    wsplit_kernel<<<(tw2 + 255) / 256, 256, 0, stream>>>(W2, root2, Wt2hi, Wt2lo, HD);

    const int gemmBlocks = (N + 63) / 64;
    const int aggBlocks  = (int)(((size_t)N * 64 + 255) / 256);
    const int NH = N * HD;

    // ---- layer 1 (K=128) ----
    gemm_mfma<128, true><<<gemmBlocks, 256, 0, stream>>>(Xhi, Xlo, Wt1hi, Wt1lo,
                                                         (unsigned short*)nullptr, accb,
                                                         R_REL, 1, N);   // accb = x @ root1
    for (int r0 = 0; r0 < R_REL; r0 += C) {
        int cc = min(C, R_REL - r0);
        gemm_mfma<128, false><<<gemmBlocks, 256, 0, stream>>>(Xhi, Xlo, Wt1hi, Wt1lo,
                                                              h_chunk, (float*)nullptr,
                                                              r0, cc, N);
        agg_chunk_kernel<<<aggBlocks, 256, 0, stream>>>(h_chunk, rowptr, elist, invf,
                                                        accb, N, r0, cc);
    }
    fin1_kernel<<<(NH + 255) / 256, 256, 0, stream>>>(accb, b1, H1hi, H1lo, NH);

    // ---- layer 2 (K=64) ----
    gemm_mfma<64, true><<<gemmBlocks, 256, 0, stream>>>(H1hi, H1lo, Wt2hi, Wt2lo,
                                                        (unsigned short*)nullptr, accb,
                                                        R_REL, 1, N);    // accb = h1 @ root2
    for (int r0 = 0; r0 < R_REL; r0 += C) {
        int cc = min(C, R_REL - r0);
        gemm_mfma<64, false><<<gemmBlocks, 256, 0, stream>>>(H1hi, H1lo, Wt2hi, Wt2lo,
                                                             h_chunk, (float*)nullptr,
                                                             r0, cc, N);
        agg_chunk_kernel<<<aggBlocks, 256, 0, stream>>>(h_chunk, rowptr, elist, invf,
                                                        accb, N, r0, cc);
    }

    // ---- pool (fused relu+bias) + classify ----
    int poolWaves = (N + 255) / 256;
    pool_kernel<<<(poolWaves + 3) / 4, 256, 0, stream>>>(accb, b2, batch, pooled, gcnt, N);
    cls_kernel<<<1, 64, 0, stream>>>(pooled, gcnt, cls_w, cls_b, (float*)d_out);
}

// Round 5
// 1115.636 us; speedup vs baseline: 2.8081x; 1.2589x over previous
//
#include <hip/hip_runtime.h>

#define R_REL 10
#define HD 64   // hidden dim, fixed by problem
#define BSH 9   // bucket shift: 512 dst per bucket; N<=131072 -> <=256 buckets

typedef __attribute__((ext_vector_type(8))) short short8;
typedef __attribute__((ext_vector_type(4))) float floatx4;
typedef __attribute__((ext_vector_type(8))) unsigned short ushort8;

__device__ inline unsigned short f32_to_bf16_rne(float f) {
    unsigned int u = __float_as_uint(f);
    unsigned int r = (u + 0x7FFFu + ((u >> 16) & 1u)) >> 16;
    return (unsigned short)r;
}
__device__ inline float bf16_to_f32(unsigned short h) {
    return __uint_as_float(((unsigned int)h) << 16);
}

// ================= bucketed CSR build =================
// phase 1: per-bucket edge counts (LDS pre-aggregated)
__global__ __launch_bounds__(256) void bhist_kernel(const int* __restrict__ dst,
                                                    int* __restrict__ bcnt, int E) {
    __shared__ int l[256];
    l[threadIdx.x] = 0;
    __syncthreads();
    int e0 = blockIdx.x * 4096;
    for (int i = threadIdx.x; i < 4096; i += 256) {
        int e = e0 + i;
        if (e < E) atomicAdd(&l[dst[e] >> BSH], 1);
    }
    __syncthreads();
    int c = l[threadIdx.x];
    if (c) atomicAdd(&bcnt[threadIdx.x], c);
}

// phase 2: scan 256 bucket counts (single block), init gcursor
__global__ void bscan_kernel(const int* __restrict__ bcnt, int* __restrict__ boff,
                             int* __restrict__ gcursor, int NBK, int E) {
    int t = threadIdx.x;
    int v = (t < NBK) ? bcnt[t] : 0;
    __shared__ int tmp[256];
    tmp[t] = v;
    __syncthreads();
    for (int off = 1; off < 256; off <<= 1) {
        int u = (t >= off) ? tmp[t - off] : 0;
        __syncthreads();
        tmp[t] += u;
        __syncthreads();
    }
    int excl = tmp[t] - v;
    if (t < NBK) { boff[t] = excl; gcursor[t] = excl; }
    if (t == 0) boff[NBK] = E;
}

// phase 3: scatter edges into bucket-grouped staging, block-local slices
__global__ __launch_bounds__(256) void bscatter_kernel(const int* __restrict__ src,
                                                       const int* __restrict__ dst,
                                                       const int* __restrict__ et,
                                                       int* __restrict__ gcursor,
                                                       int2* __restrict__ staged, int E) {
    __shared__ int lcnt[256];
    __shared__ int lbase[256];
    int t = threadIdx.x;
    int e0 = blockIdx.x * 4096;
    lcnt[t] = 0;
    __syncthreads();
    for (int i = t; i < 4096; i += 256) {
        int e = e0 + i;
        if (e < E) atomicAdd(&lcnt[dst[e] >> BSH], 1);
    }
    __syncthreads();
    int c = lcnt[t];
    lbase[t] = (c > 0) ? atomicAdd(&gcursor[t], c) : 0;
    lcnt[t] = 0;
    __syncthreads();
    for (int i = t; i < 4096; i += 256) {
        int e = e0 + i;
        if (e < E) {
            int dd = dst[e];
            int bk = dd >> BSH;
            int pos = lbase[bk] + atomicAdd(&lcnt[bk], 1);
            staged[pos] = make_int2(src[e], dd * R_REL + et[e]);
        }
    }
}

// phase 4: per-bucket key histogram (atomics hit a ~20KB L2-hot window)
__global__ __launch_bounds__(256) void hist2_kernel(const int2* __restrict__ staged,
                                                    const int* __restrict__ boff,
                                                    int* __restrict__ keycnt) {
    int b = blockIdx.x >> 2, part = blockIdx.x & 3;
    int s0 = boff[b], s1 = boff[b + 1];
    int total = s1 - s0, q = (total + 3) >> 2;
    int a0 = s0 + part * q, a1 = min(a0 + q, s1);
    for (int i = a0 + threadIdx.x; i < a1; i += 256)
        atomicAdd(&keycnt[staged[i].y], 1);
}

// phase 6: per-bucket fill (cursor atomics + elist writes both L2-hot)
__global__ __launch_bounds__(256) void fill2_kernel(const int2* __restrict__ staged,
                                                    const int* __restrict__ boff,
                                                    int* __restrict__ cursor,
                                                    int* __restrict__ elist) {
    int b = blockIdx.x >> 2, part = blockIdx.x & 3;
    int s0 = boff[b], s1 = boff[b + 1];
    int total = s1 - s0, q = (total + 3) >> 2;
    int a0 = s0 + part * q, a1 = min(a0 + q, s1);
    for (int i = a0 + threadIdx.x; i < a1; i += 256) {
        int2 p = staged[i];
        int slot = atomicAdd(&cursor[p.y], 1);
        elist[slot] = p.x;
    }
}

// ---------------- 3-kernel exclusive scan over M=N*R ints ----------------
__global__ void scan1_kernel(const int* __restrict__ cnt, int* __restrict__ bsum, int M) {
    int b = blockIdx.x, tid = threadIdx.x;
    int base = b * 1024 + tid * 4;
    int s = 0;
#pragma unroll
    for (int j = 0; j < 4; ++j) { int i = base + j; if (i < M) s += cnt[i]; }
    for (int off = 32; off > 0; off >>= 1) s += __shfl_down(s, off);
    __shared__ int wsum[4];
    int lane = tid & 63, wid = tid >> 6;
    if (lane == 0) wsum[wid] = s;
    __syncthreads();
    if (tid == 0) bsum[b] = wsum[0] + wsum[1] + wsum[2] + wsum[3];
}

__global__ void scan2_kernel(const int* __restrict__ bsum, int* __restrict__ boff, int NB) {
    int tid = threadIdx.x;           // 1024 threads
    int lane = tid & 63, wid = tid >> 6;
    int v = (tid < NB) ? bsum[tid] : 0;
    int x = v;
    for (int off = 1; off < 64; off <<= 1) { int u = __shfl_up(x, off); if (lane >= off) x += u; }
    __shared__ int wsum[16];
    if (lane == 63) wsum[wid] = x;
    __syncthreads();
    int woff = 0;
    for (int w = 0; w < wid; ++w) woff += wsum[w];
    if (tid < NB) boff[tid] = x + woff - v;   // exclusive
}

__global__ void scan3_kernel(const int* __restrict__ cnt, const int* __restrict__ boff,
                             int* __restrict__ rowptr, int* __restrict__ cursor, int M) {
    int b = blockIdx.x, tid = threadIdx.x;
    int base = b * 1024 + tid * 4;
    int c[4]; int s = 0;
#pragma unroll
    for (int j = 0; j < 4; ++j) { int i = base + j; c[j] = (i < M) ? cnt[i] : 0; s += c[j]; }
    int lane = tid & 63, wid = tid >> 6;
    int x = s;
    for (int off = 1; off < 64; off <<= 1) { int u = __shfl_up(x, off); if (lane >= off) x += u; }
    __shared__ int wsum[4];
    if (lane == 63) wsum[wid] = x;
    __syncthreads();
    int woff = 0;
    for (int w = 0; w < wid; ++w) woff += wsum[w];
    int run = boff[b] + x + woff - s;        // exclusive start for this thread
#pragma unroll
    for (int j = 0; j < 4; ++j) {
        int i = base + j;
        if (i < M) {
            rowptr[i] = run; cursor[i] = run; run += c[j];
            if (i == M - 1) rowptr[M] = run;
        }
    }
}

// in-place: read int count, write float 1/max(cnt,1) into same buffer
__global__ void inv_kernel(int* __restrict__ cnt, int M) {
    int i = blockIdx.x * 256 + threadIdx.x;
    if (i < M) {
        float c = (float)cnt[i];
        ((float*)cnt)[i] = 1.0f / fmaxf(c, 1.0f);
    }
}

// ---------------- hi/lo bf16 split of a f32 array ----------------
__global__ void split_kernel(const float* __restrict__ src, unsigned short* __restrict__ hi,
                             unsigned short* __restrict__ lo, int n) {
    int i = blockIdx.x * 256 + threadIdx.x;
    if (i < n) {
        float v = src[i];
        unsigned short h = f32_to_bf16_rne(v);
        hi[i] = h;
        lo[i] = f32_to_bf16_rne(v - bf16_to_f32(h));
    }
}

// W [R][K][HD] + root [K][HD] f32  ->  Wt hi/lo bf16 [(R+1)][HD][K]  (n-major, k contiguous)
__global__ void wsplit_kernel(const float* __restrict__ W, const float* __restrict__ root,
                              unsigned short* __restrict__ hi, unsigned short* __restrict__ lo,
                              int K) {
    int idx = blockIdx.x * 256 + threadIdx.x;
    int total = (R_REL + 1) * HD * K;
    if (idx >= total) return;
    int rel = idx / (HD * K);
    int rem = idx - rel * HD * K;
    int n = rem / K, k = rem - n * K;
    float v = (rel < R_REL) ? W[((size_t)rel * K + k) * HD + n] : root[(size_t)k * HD + n];
    unsigned short h = f32_to_bf16_rne(v);
    hi[idx] = h;
    lo[idx] = f32_to_bf16_rne(v - bf16_to_f32(h));
}

// ---------------- MFMA GEMM: per block 64 nodes x 64 outs, nrel relations ----
template <int K, bool F32OUT>
__global__ __launch_bounds__(256) void gemm_mfma(const unsigned short* __restrict__ Xhi,
                                                 const unsigned short* __restrict__ Xlo,
                                                 const unsigned short* __restrict__ Wthi,
                                                 const unsigned short* __restrict__ Wtlo,
                                                 unsigned short* __restrict__ hout,
                                                 float* __restrict__ fout,
                                                 int r0, int nrel, int N) {
    constexpr int LDK = K + 8;
    __shared__ unsigned short xs_hi[64 * LDK];
    __shared__ unsigned short xs_lo[64 * LDK];
    const int tid = threadIdx.x;
    const int w = tid >> 6, lane = tid & 63;
    const int n0 = blockIdx.x * 64;
    constexpr int CH = K / 8;          // 16B chunks per row
    constexpr int RPI = 256 / CH;      // rows staged per iteration
#pragma unroll
    for (int it = 0; it < 64 / RPI; ++it) {
        int row = it * RPI + tid / CH;
        int ck = (tid & (CH - 1)) * 8;
        int node = n0 + row;
        ushort8 vh, vl;
#pragma unroll
        for (int q = 0; q < 8; ++q) { vh[q] = 0; vl[q] = 0; }
        if (node < N) {
            vh = *(const ushort8*)(Xhi + (size_t)node * K + ck);
            vl = *(const ushort8*)(Xlo + (size_t)node * K + ck);
        }
        *(ushort8*)&xs_hi[row * LDK + ck] = vh;
        *(ushort8*)&xs_lo[row * LDK + ck] = vl;
    }
    __syncthreads();
    const int quad = lane >> 4, l16 = lane & 15;
    const int colg = w * 16 + l16;
    for (int c = 0; c < nrel; ++c) {
        int rel = r0 + c;
        const unsigned short* bh_base = Wthi + ((size_t)rel * HD + colg) * K + quad * 8;
        const unsigned short* bl_base = Wtlo + ((size_t)rel * HD + colg) * K + quad * 8;
        floatx4 zero = {0.f, 0.f, 0.f, 0.f};
        floatx4 acc[4];
#pragma unroll
        for (int mt = 0; mt < 4; ++mt) acc[mt] = zero;
#pragma unroll
        for (int s = 0; s < K / 32; ++s) {
            short8 bh = *(const short8*)(bh_base + s * 32);
            short8 bl = *(const short8*)(bl_base + s * 32);
            int ko = s * 32 + quad * 8;
#pragma unroll
            for (int mt = 0; mt < 4; ++mt) {
                short8 ah = *(const short8*)&xs_hi[(mt * 16 + l16) * LDK + ko];
                short8 al = *(const short8*)&xs_lo[(mt * 16 + l16) * LDK + ko];
                acc[mt] = __builtin_amdgcn_mfma_f32_16x16x32_bf16(ah, bh, acc[mt], 0, 0, 0);
                acc[mt] = __builtin_amdgcn_mfma_f32_16x16x32_bf16(al, bh, acc[mt], 0, 0, 0);
                acc[mt] = __builtin_amdgcn_mfma_f32_16x16x32_bf16(ah, bl, acc[mt], 0, 0, 0);
            }
        }
        // C/D layout: col = lane&15, row = quad*4 + reg  [HW-verified]
#pragma unroll
        for (int mt = 0; mt < 4; ++mt) {
#pragma unroll
            for (int r = 0; r < 4; ++r) {
                int node = n0 + mt * 16 + quad * 4 + r;
                if (node < N) {
                    if (F32OUT)
                        fout[(size_t)node * HD + colg] = acc[mt][r];
                    else
                        hout[(size_t)c * N * HD + (size_t)node * HD + colg] =
                            f32_to_bf16_rne(acc[mt][r]);
                }
            }
        }
    }
}

// ---------------- cooperative chunked aggregation: one wave per dst ----------
// Chunk edges for dst d are CONTIGUOUS: rowptr[d*R+r0] .. rowptr[d*R+r0+cc].
// Lane j owns edge e0+j: coalesced elist load, relation via shuffled boundaries,
// then broadcast row offsets and pipeline 4 independent 128B gathers.
__global__ __launch_bounds__(256) void agg_chunk_kernel(const unsigned short* __restrict__ hc,
                                                        const int* __restrict__ rowptr,
                                                        const int* __restrict__ elist,
                                                        const float* __restrict__ inv,
                                                        float* __restrict__ acc,
                                                        int N, int r0, int cc) {
    int gid = blockIdx.x * 256 + threadIdx.x;
    int d = gid >> 6;
    int lane = threadIdx.x & 63;
    if (d >= N) return;
    int base = d * R_REL + r0;
    int bsel = min(lane, cc);
    int rp = rowptr[base + bsel];            // lane r in [0,cc]: boundary r
    float iv = inv[base + min(lane, cc - 1)];// lane r in [0,cc-1]: weight of rel r
    int e0 = __shfl(rp, 0);
    int e1 = __shfl(rp, cc);
    int ne = e1 - e0;
    if (ne == 0) return;
    float sum = 0.f;
    for (int rbase = 0; rbase < ne; rbase += 64) {
        int nthis = min(64, ne - rbase);
        int e = e0 + rbase + lane;
        int srcj = (lane < nthis) ? elist[e] : 0;
        int rel = 0;
        for (int r = 1; r <= cc; ++r) rel += (__shfl(rp, r) <= e) ? 1 : 0;
        rel = min(rel, cc - 1);                       // clamp stray lanes
        float wj = __shfl(iv, rel);
        int off = (rel * N + srcj) * HD;              // fits int: < 10*1e5*64
        int j = 0;
        for (; j + 4 <= nthis; j += 4) {
            int o0 = __shfl(off, j), o1 = __shfl(off, j + 1);
            int o2 = __shfl(off, j + 2), o3 = __shfl(off, j + 3);
            float w0 = __shfl(wj, j), w1 = __shfl(wj, j + 1);
            float w2 = __shfl(wj, j + 2), w3 = __shfl(wj, j + 3);
            float v0 = bf16_to_f32(hc[o0 + lane]);
            float v1 = bf16_to_f32(hc[o1 + lane]);
            float v2 = bf16_to_f32(hc[o2 + lane]);
            float v3 = bf16_to_f32(hc[o3 + lane]);
            sum += w0 * v0; sum += w1 * v1; sum += w2 * v2; sum += w3 * v3;
        }
        for (; j < nthis; ++j) {
            int o = __shfl(off, j);
            float ww = __shfl(wj, j);
            sum += ww * bf16_to_f32(hc[o + lane]);
        }
    }
    acc[(size_t)d * HD + lane] += sum;
}

// ---------------- finalize layer 1: relu(acc+b) -> bf16 hi/lo ----------------
__global__ void fin1_kernel(const float* __restrict__ acc, const float* __restrict__ bias,
                            unsigned short* __restrict__ hi, unsigned short* __restrict__ lo,
                            int NH) {
    int i = blockIdx.x * 256 + threadIdx.x;
    if (i < NH) {
        float v = fmaxf(acc[i] + bias[i & (HD - 1)], 0.f);
        unsigned short h = f32_to_bf16_rne(v);
        hi[i] = h;
        lo[i] = f32_to_bf16_rne(v - bf16_to_f32(h));
    }
}

// ---------------- mean pool, fused relu+bias: wave per 256 sorted nodes -------
__global__ __launch_bounds__(256) void pool_kernel(const float* __restrict__ acc,
                                                   const float* __restrict__ bias,
                                                   const int* __restrict__ batch,
                                                   float* __restrict__ pooled,
                                                   float* __restrict__ gcnt, int N) {
    int w = blockIdx.x * 4 + (threadIdx.x >> 6);
    int lane = threadIdx.x & 63;
    int base = w * 256;
    if (base >= N) return;
    float b = bias[lane];
    int cur = -1; float sum = 0.f; int cnt = 0;
    int end = min(base + 256, N);
    for (int n = base; n < end; ++n) {
        int g = batch[n];
        if (g != cur) {
            if (cur >= 0) {
                atomicAdd(&pooled[cur * HD + lane], sum);
                if (lane == 0) atomicAdd(&gcnt[cur], (float)cnt);
            }
            cur = g; sum = 0.f; cnt = 0;
        }
        sum += fmaxf(acc[(size_t)n * HD + lane] + b, 0.f);
        cnt++;
    }
    if (cur >= 0) {
        atomicAdd(&pooled[cur * HD + lane], sum);
        if (lane == 0) atomicAdd(&gcnt[cur], (float)cnt);
    }
}

__global__ void cls_kernel(const float* __restrict__ pooled, const float* __restrict__ gcnt,
                           const float* __restrict__ cls_w, const float* __restrict__ cls_b,
                           float* __restrict__ out) {
    int g = threadIdx.x;   // 64 graphs
    float invc = 1.0f / fmaxf(gcnt[g], 1.0f);
    float acc = 0.f;
    for (int j = 0; j < 64; ++j) acc += pooled[g * 64 + j] * cls_w[j];
    out[g] = acc * invc + cls_b[0];
}

extern "C" void kernel_launch(void* const* d_in, const int* in_sizes, int n_in,
                              void* d_out, int out_size, void* d_ws, size_t ws_size,
                              hipStream_t stream) {
    const float* x     = (const float*)d_in[0];
    const int*   eidx  = (const int*)d_in[1];
    const int*   et    = (const int*)d_in[2];
    const int*   batch = (const int*)d_in[3];
    const float* W1    = (const float*)d_in[4];
    const float* root1 = (const float*)d_in[5];
    const float* b1    = (const float*)d_in[6];
    const float* W2    = (const float*)d_in[7];
    const float* root2 = (const float*)d_in[8];
    const float* b2    = (const float*)d_in[9];
    const float* cls_w = (const float*)d_in[10];
    const float* cls_b = (const float*)d_in[11];

    const int N = in_sizes[3];
    const int E = in_sizes[2];
    const int M = N * R_REL;
    const int NB = (M + 1023) / 1024;
    const int NBK = (N + (1 << BSH) - 1) >> BSH;   // <=256 buckets
    const int* srcp = eidx;
    const int* dstp = eidx + E;

    char* ws = (char*)d_ws;
    size_t off = 0;
    auto alloc = [&](size_t bytes) -> void* {
        void* p = ws + off;
        off = (off + bytes + 255) & ~(size_t)255;
        return p;
    };
    // fixed buffers (~129 MB)
    unsigned short* Xhi  = (unsigned short*)alloc((size_t)N * 128 * 2);   // 25.6 MB
    unsigned short* Xlo  = (unsigned short*)alloc((size_t)N * 128 * 2);   // 25.6 MB
    unsigned short* H1hi = (unsigned short*)alloc((size_t)N * HD * 2);    // 12.8 MB
    unsigned short* H1lo = (unsigned short*)alloc((size_t)N * HD * 2);    // 12.8 MB
    float*          accb = (float*)alloc((size_t)N * HD * 4);             // 25.6 MB
    unsigned short* Wt1hi = (unsigned short*)alloc((size_t)(R_REL + 1) * HD * 128 * 2);
    unsigned short* Wt1lo = (unsigned short*)alloc((size_t)(R_REL + 1) * HD * 128 * 2);
    unsigned short* Wt2hi = (unsigned short*)alloc((size_t)(R_REL + 1) * HD * HD * 2);
    unsigned short* Wt2lo = (unsigned short*)alloc((size_t)(R_REL + 1) * HD * HD * 2);
    int*   keycnt = (int*)alloc((size_t)M * 4);
    int*   rowptr = (int*)alloc((size_t)(M + 1) * 4);
    int*   cursor = (int*)alloc((size_t)M * 4);
    int*   elist  = (int*)alloc((size_t)E * 4);                           // 12.8 MB
    int*   bsum   = (int*)alloc((size_t)NB * 4);
    int*   bofs   = (int*)alloc((size_t)NB * 4);
    int*   bcnt   = (int*)alloc(256 * 4);
    int*   bboff  = (int*)alloc(257 * 4);
    int*   gcur   = (int*)alloc(256 * 4);
    float* pooled = (float*)alloc((size_t)(64 * HD + 64) * 4);
    float* gcnt   = pooled + 64 * HD;
    float* invf   = (float*)keycnt;

    // staged bucket-grouped (src,key) pairs alias Xhi: E*8 <= N*128*2 for this
    // problem (both 25.6 MB); staged fully consumed (hist2+fill2) before
    // split_kernel writes Xhi -- stream-ordered, safe.
    int2* staged = (int2*)Xhi;

    // relation-chunk buffer from whatever workspace remains (12.8 MB per relation)
    size_t per_rel = ((size_t)N * HD * 2 + 255) & ~(size_t)255;
    size_t remain = (ws_size > off) ? (ws_size - off) : 0;
    int C = (int)(remain / per_rel);
    if (C < 1) C = 1;
    if (C > R_REL) C = R_REL;
    unsigned short* h_chunk = (unsigned short*)alloc((size_t)C * per_rel);

    hipMemsetAsync(keycnt, 0, (size_t)M * 4, stream);
    hipMemsetAsync(bcnt, 0, 256 * 4, stream);
    hipMemsetAsync(pooled, 0, (size_t)(64 * HD + 64) * 4, stream);

    // ---- bucketed CSR build ----
    int nchunks = (E + 4095) / 4096;
    bhist_kernel<<<nchunks, 256, 0, stream>>>(dstp, bcnt, E);
    bscan_kernel<<<1, 256, 0, stream>>>(bcnt, bboff, gcur, NBK, E);
    bscatter_kernel<<<nchunks, 256, 0, stream>>>(srcp, dstp, et, gcur, staged, E);
    hist2_kernel<<<NBK * 4, 256, 0, stream>>>(staged, bboff, keycnt);
    scan1_kernel<<<NB, 256, 0, stream>>>(keycnt, bsum, M);
    scan2_kernel<<<1, 1024, 0, stream>>>(bsum, bofs, NB);
    scan3_kernel<<<NB, 256, 0, stream>>>(keycnt, bofs, rowptr, cursor, M);
    inv_kernel<<<(M + 255) / 256, 256, 0, stream>>>(keycnt, M);
    fill2_kernel<<<NBK * 4, 256, 0, stream>>>(staged, bboff, cursor, elist);

    // ---- precision-split operands (after staged is dead) ----
    int NK = N * 128;
    split_kernel<<<(NK + 255) / 256, 256, 0, stream>>>(x, Xhi, Xlo, NK);
    int tw1 = (R_REL + 1) * HD * 128, tw2 = (R_REL + 1) * HD * HD;
    wsplit_kernel<<<(tw1 + 255) / 256, 256, 0, stream>>>(W1, root1, Wt1hi, Wt1lo, 128);
    wsplit_kernel<<<(tw2 + 255) / 256, 256, 0, stream>>>(W2, root2, Wt2hi, Wt2lo, HD);

    const int gemmBlocks = (N + 63) / 64;
    const int aggBlocks  = (int)(((size_t)N * 64 + 255) / 256);
    const int NH = N * HD;

    // ---- layer 1 (K=128) ----
    gemm_mfma<128, true><<<gemmBlocks, 256, 0, stream>>>(Xhi, Xlo, Wt1hi, Wt1lo,
                                                         (unsigned short*)nullptr, accb,
                                                         R_REL, 1, N);   // accb = x @ root1
    for (int r0 = 0; r0 < R_REL; r0 += C) {
        int cc = min(C, R_REL - r0);
        gemm_mfma<128, false><<<gemmBlocks, 256, 0, stream>>>(Xhi, Xlo, Wt1hi, Wt1lo,
                                                              h_chunk, (float*)nullptr,
                                                              r0, cc, N);
        agg_chunk_kernel<<<aggBlocks, 256, 0, stream>>>(h_chunk, rowptr, elist, invf,
                                                        accb, N, r0, cc);
    }
    fin1_kernel<<<(NH + 255) / 256, 256, 0, stream>>>(accb, b1, H1hi, H1lo, NH);

    // ---- layer 2 (K=64) ----
    gemm_mfma<64, true><<<gemmBlocks, 256, 0, stream>>>(H1hi, H1lo, Wt2hi, Wt2lo,
                                                        (unsigned short*)nullptr, accb,
                                                        R_REL, 1, N);    // accb = h1 @ root2
    for (int r0 = 0; r0 < R_REL; r0 += C) {
        int cc = min(C, R_REL - r0);
        gemm_mfma<64, false><<<gemmBlocks, 256, 0, stream>>>(H1hi, H1lo, Wt2hi, Wt2lo,
                                                             h_chunk, (float*)nullptr,
                                                             r0, cc, N);
        agg_chunk_kernel<<<aggBlocks, 256, 0, stream>>>(h_chunk, rowptr, elist, invf,
                                                        accb, N, r0, cc);
    }

    // ---- pool (fused relu+bias) + classify ----
    int poolWaves = (N + 255) / 256;
    pool_kernel<<<(poolWaves + 3) / 4, 256, 0, stream>>>(accb, b2, batch, pooled, gcnt, N);
    cls_kernel<<<1, 64, 0, stream>>>(pooled, gcnt, cls_w, cls_b, (float*)d_out);
}

// Round 6
// 761.552 us; speedup vs baseline: 4.1138x; 1.4650x over previous
//
#include <hip/hip_runtime.h>

#define R_REL 10
#define HD 64    // hidden dim, fixed by problem
#define BSH 8    // bucket shift: 256 dst per bucket; N<=131072 -> <=512 buckets
#define KPB (256 * R_REL)   // 2560 keys per bucket
#define SORT_CAP 12288      // LDS edge capacity per bucket (mean 8192, +45 sigma)

typedef __attribute__((ext_vector_type(8))) short short8;
typedef __attribute__((ext_vector_type(4))) float floatx4;
typedef __attribute__((ext_vector_type(8))) unsigned short ushort8;

__device__ inline unsigned short f32_to_bf16_rne(float f) {
    unsigned int u = __float_as_uint(f);
    unsigned int r = (u + 0x7FFFu + ((u >> 16) & 1u)) >> 16;
    return (unsigned short)r;
}
__device__ inline float bf16_to_f32(unsigned short h) {
    return __uint_as_float(((unsigned int)h) << 16);
}

// ================= bucketed CSR build =================
// phase 1: per-bucket edge counts (LDS pre-aggregated), 512 buckets
__global__ __launch_bounds__(256) void bhist_kernel(const int* __restrict__ dst,
                                                    int* __restrict__ bcnt, int E) {
    __shared__ int l[512];
    int t = threadIdx.x;
    l[t] = 0; l[t + 256] = 0;
    __syncthreads();
    int e0 = blockIdx.x * 4096;
    for (int i = t; i < 4096; i += 256) {
        int e = e0 + i;
        if (e < E) atomicAdd(&l[dst[e] >> BSH], 1);
    }
    __syncthreads();
    if (l[t]) atomicAdd(&bcnt[t], l[t]);
    if (l[t + 256]) atomicAdd(&bcnt[t + 256], l[t + 256]);
}

// phase 2: scan 512 bucket counts (single block of 512), init gcursor
__global__ void bscan_kernel(const int* __restrict__ bcnt, int* __restrict__ boff,
                             int* __restrict__ gcursor, int NBK, int E) {
    int t = threadIdx.x;   // 512 threads
    int v = (t < NBK) ? bcnt[t] : 0;
    __shared__ int tmp[512];
    tmp[t] = v;
    __syncthreads();
    for (int off = 1; off < 512; off <<= 1) {
        int u = (t >= off) ? tmp[t - off] : 0;
        __syncthreads();
        tmp[t] += u;
        __syncthreads();
    }
    int excl = tmp[t] - v;
    if (t < NBK) { boff[t] = excl; gcursor[t] = excl; }
    if (t == 0) boff[NBK] = E;
}

// phase 3: scatter edges into bucket-grouped staging, block-local slices
__global__ __launch_bounds__(256) void bscatter_kernel(const int* __restrict__ src,
                                                       const int* __restrict__ dst,
                                                       const int* __restrict__ et,
                                                       int* __restrict__ gcursor,
                                                       int2* __restrict__ staged, int E) {
    __shared__ int lcnt[512];
    __shared__ int lbase[512];
    int t = threadIdx.x;
    int e0 = blockIdx.x * 4096;
    lcnt[t] = 0; lcnt[t + 256] = 0;
    __syncthreads();
    for (int i = t; i < 4096; i += 256) {
        int e = e0 + i;
        if (e < E) atomicAdd(&lcnt[dst[e] >> BSH], 1);
    }
    __syncthreads();
    int c0 = lcnt[t], c1 = lcnt[t + 256];
    lbase[t]       = (c0 > 0) ? atomicAdd(&gcursor[t], c0) : 0;
    lbase[t + 256] = (c1 > 0) ? atomicAdd(&gcursor[t + 256], c1) : 0;
    lcnt[t] = 0; lcnt[t + 256] = 0;
    __syncthreads();
    for (int i = t; i < 4096; i += 256) {
        int e = e0 + i;
        if (e < E) {
            int dd = dst[e];
            int bk = dd >> BSH;
            int pos = lbase[bk] + atomicAdd(&lcnt[bk], 1);
            staged[pos] = make_int2(src[e], dd * R_REL + et[e]);
        }
    }
}

// phase 4: per-bucket LDS counting sort -> coalesced elist + keycnt writes.
// One block per bucket. rowptr[keylo_b] == bboff[b], so no global cursor needed.
__global__ __launch_bounds__(256) void sortfill_kernel(const int2* __restrict__ staged,
                                                       const int* __restrict__ boff,
                                                       int* __restrict__ keycnt,
                                                       int* __restrict__ elist, int M) {
    __shared__ int hist[KPB];       // 10 KB: counts -> exclusive offsets -> cursors
    __shared__ int part[256];       // 1 KB scan partials
    __shared__ int lsrc[SORT_CAP];  // 48 KB sorted src values
    int t = threadIdx.x;
    int b = blockIdx.x;
    int s0 = boff[b], s1 = boff[b + 1];
    int cnt = s1 - s0;
    int keylo = b * KPB;
#pragma unroll
    for (int j = 0; j < KPB / 256; ++j) hist[t + j * 256] = 0;
    __syncthreads();
    // pass 1: histogram
    for (int i = s0 + t; i < s1; i += 256)
        atomicAdd(&hist[staged[i].y - keylo], 1);
    __syncthreads();
    // coalesced keycnt write (replaces global-atomic hist2)
    for (int j = t; j < KPB; j += 256) {
        int k = keylo + j;
        if (k < M) keycnt[k] = hist[j];
    }
    // in-place exclusive scan of hist (each thread owns 10 consecutive keys)
    int base = t * (KPB / 256);
    int c[KPB / 256];
    int s = 0;
#pragma unroll
    for (int j = 0; j < KPB / 256; ++j) { c[j] = hist[base + j]; s += c[j]; }
    part[t] = s;
    __syncthreads();
    for (int off = 1; off < 256; off <<= 1) {
        int u = (t >= off) ? part[t - off] : 0;
        __syncthreads();
        part[t] += u;
        __syncthreads();
    }
    int run = part[t] - s;   // exclusive prefix for this thread's first key
#pragma unroll
    for (int j = 0; j < KPB / 256; ++j) { hist[base + j] = run; run += c[j]; }
    __syncthreads();
    // pass 2: scatter src into LDS at sorted position (hist = running cursor)
    for (int i = s0 + t; i < s1; i += 256) {
        int2 p = staged[i];
        int pos = atomicAdd(&hist[p.y - keylo], 1);
        if (pos < SORT_CAP) lsrc[pos] = p.x;
        else elist[s0 + pos] = p.x;   // overflow fallback (never expected; stays correct)
    }
    __syncthreads();
    // pass 3: coalesced stream-out
    int m = min(cnt, SORT_CAP);
    for (int j = t; j < m; j += 256) elist[s0 + j] = lsrc[j];
}

// ---------------- 3-kernel exclusive scan over M=N*R ints ----------------
__global__ void scan1_kernel(const int* __restrict__ cnt, int* __restrict__ bsum, int M) {
    int b = blockIdx.x, tid = threadIdx.x;
    int base = b * 1024 + tid * 4;
    int s = 0;
#pragma unroll
    for (int j = 0; j < 4; ++j) { int i = base + j; if (i < M) s += cnt[i]; }
    for (int off = 32; off > 0; off >>= 1) s += __shfl_down(s, off);
    __shared__ int wsum[4];
    int lane = tid & 63, wid = tid >> 6;
    if (lane == 0) wsum[wid] = s;
    __syncthreads();
    if (tid == 0) bsum[b] = wsum[0] + wsum[1] + wsum[2] + wsum[3];
}

__global__ void scan2_kernel(const int* __restrict__ bsum, int* __restrict__ boff, int NB) {
    int tid = threadIdx.x;           // 1024 threads
    int lane = tid & 63, wid = tid >> 6;
    int v = (tid < NB) ? bsum[tid] : 0;
    int x = v;
    for (int off = 1; off < 64; off <<= 1) { int u = __shfl_up(x, off); if (lane >= off) x += u; }
    __shared__ int wsum[16];
    if (lane == 63) wsum[wid] = x;
    __syncthreads();
    int woff = 0;
    for (int w = 0; w < wid; ++w) woff += wsum[w];
    if (tid < NB) boff[tid] = x + woff - v;   // exclusive
}

__global__ void scan3_kernel(const int* __restrict__ cnt, const int* __restrict__ boff,
                             int* __restrict__ rowptr, int M) {
    int b = blockIdx.x, tid = threadIdx.x;
    int base = b * 1024 + tid * 4;
    int c[4]; int s = 0;
#pragma unroll
    for (int j = 0; j < 4; ++j) { int i = base + j; c[j] = (i < M) ? cnt[i] : 0; s += c[j]; }
    int lane = tid & 63, wid = tid >> 6;
    int x = s;
    for (int off = 1; off < 64; off <<= 1) { int u = __shfl_up(x, off); if (lane >= off) x += u; }
    __shared__ int wsum[4];
    if (lane == 63) wsum[wid] = x;
    __syncthreads();
    int woff = 0;
    for (int w = 0; w < wid; ++w) woff += wsum[w];
    int run = boff[b] + x + woff - s;        // exclusive start for this thread
#pragma unroll
    for (int j = 0; j < 4; ++j) {
        int i = base + j;
        if (i < M) {
            rowptr[i] = run; run += c[j];
            if (i == M - 1) rowptr[M] = run;
        }
    }
}

// in-place: read int count, write float 1/max(cnt,1) into same buffer
__global__ void inv_kernel(int* __restrict__ cnt, int M) {
    int i = blockIdx.x * 256 + threadIdx.x;
    if (i < M) {
        float c = (float)cnt[i];
        ((float*)cnt)[i] = 1.0f / fmaxf(c, 1.0f);
    }
}

// ---------------- hi/lo bf16 split of a f32 array ----------------
__global__ void split_kernel(const float* __restrict__ src, unsigned short* __restrict__ hi,
                             unsigned short* __restrict__ lo, int n) {
    int i = blockIdx.x * 256 + threadIdx.x;
    if (i < n) {
        float v = src[i];
        unsigned short h = f32_to_bf16_rne(v);
        hi[i] = h;
        lo[i] = f32_to_bf16_rne(v - bf16_to_f32(h));
    }
}

// W [R][K][HD] + root [K][HD] f32  ->  Wt hi/lo bf16 [(R+1)][HD][K]  (n-major, k contiguous)
__global__ void wsplit_kernel(const float* __restrict__ W, const float* __restrict__ root,
                              unsigned short* __restrict__ hi, unsigned short* __restrict__ lo,
                              int K) {
    int idx = blockIdx.x * 256 + threadIdx.x;
    int total = (R_REL + 1) * HD * K;
    if (idx >= total) return;
    int rel = idx / (HD * K);
    int rem = idx - rel * HD * K;
    int n = rem / K, k = rem - n * K;
    float v = (rel < R_REL) ? W[((size_t)rel * K + k) * HD + n] : root[(size_t)k * HD + n];
    unsigned short h = f32_to_bf16_rne(v);
    hi[idx] = h;
    lo[idx] = f32_to_bf16_rne(v - bf16_to_f32(h));
}

// ---------------- MFMA GEMM: per block 64 nodes x 64 outs, nrel relations ----
template <int K, bool F32OUT>
__global__ __launch_bounds__(256) void gemm_mfma(const unsigned short* __restrict__ Xhi,
                                                 const unsigned short* __restrict__ Xlo,
                                                 const unsigned short* __restrict__ Wthi,
                                                 const unsigned short* __restrict__ Wtlo,
                                                 unsigned short* __restrict__ hout,
                                                 float* __restrict__ fout,
                                                 int r0, int nrel, int N) {
    constexpr int LDK = K + 8;
    __shared__ unsigned short xs_hi[64 * LDK];
    __shared__ unsigned short xs_lo[64 * LDK];
    const int tid = threadIdx.x;
    const int w = tid >> 6, lane = tid & 63;
    const int n0 = blockIdx.x * 64;
    constexpr int CH = K / 8;          // 16B chunks per row
    constexpr int RPI = 256 / CH;      // rows staged per iteration
#pragma unroll
    for (int it = 0; it < 64 / RPI; ++it) {
        int row = it * RPI + tid / CH;
        int ck = (tid & (CH - 1)) * 8;
        int node = n0 + row;
        ushort8 vh, vl;
#pragma unroll
        for (int q = 0; q < 8; ++q) { vh[q] = 0; vl[q] = 0; }
        if (node < N) {
            vh = *(const ushort8*)(Xhi + (size_t)node * K + ck);
            vl = *(const ushort8*)(Xlo + (size_t)node * K + ck);
        }
        *(ushort8*)&xs_hi[row * LDK + ck] = vh;
        *(ushort8*)&xs_lo[row * LDK + ck] = vl;
    }
    __syncthreads();
    const int quad = lane >> 4, l16 = lane & 15;
    const int colg = w * 16 + l16;
    for (int c = 0; c < nrel; ++c) {
        int rel = r0 + c;
        const unsigned short* bh_base = Wthi + ((size_t)rel * HD + colg) * K + quad * 8;
        const unsigned short* bl_base = Wtlo + ((size_t)rel * HD + colg) * K + quad * 8;
        floatx4 zero = {0.f, 0.f, 0.f, 0.f};
        floatx4 acc[4];
#pragma unroll
        for (int mt = 0; mt < 4; ++mt) acc[mt] = zero;
#pragma unroll
        for (int s = 0; s < K / 32; ++s) {
            short8 bh = *(const short8*)(bh_base + s * 32);
            short8 bl = *(const short8*)(bl_base + s * 32);
            int ko = s * 32 + quad * 8;
#pragma unroll
            for (int mt = 0; mt < 4; ++mt) {
                short8 ah = *(const short8*)&xs_hi[(mt * 16 + l16) * LDK + ko];
                short8 al = *(const short8*)&xs_lo[(mt * 16 + l16) * LDK + ko];
                acc[mt] = __builtin_amdgcn_mfma_f32_16x16x32_bf16(ah, bh, acc[mt], 0, 0, 0);
                acc[mt] = __builtin_amdgcn_mfma_f32_16x16x32_bf16(al, bh, acc[mt], 0, 0, 0);
                acc[mt] = __builtin_amdgcn_mfma_f32_16x16x32_bf16(ah, bl, acc[mt], 0, 0, 0);
            }
        }
        // C/D layout: col = lane&15, row = quad*4 + reg  [HW-verified]
#pragma unroll
        for (int mt = 0; mt < 4; ++mt) {
#pragma unroll
            for (int r = 0; r < 4; ++r) {
                int node = n0 + mt * 16 + quad * 4 + r;
                if (node < N) {
                    if (F32OUT)
                        fout[(size_t)node * HD + colg] = acc[mt][r];
                    else
                        hout[(size_t)c * N * HD + (size_t)node * HD + colg] =
                            f32_to_bf16_rne(acc[mt][r]);
                }
            }
        }
    }
}

// ---------------- cooperative chunked aggregation: one wave per dst ----------
__global__ __launch_bounds__(256) void agg_chunk_kernel(const unsigned short* __restrict__ hc,
                                                        const int* __restrict__ rowptr,
                                                        const int* __restrict__ elist,
                                                        const float* __restrict__ inv,
                                                        float* __restrict__ acc,
                                                        int N, int r0, int cc) {
    int gid = blockIdx.x * 256 + threadIdx.x;
    int d = gid >> 6;
    int lane = threadIdx.x & 63;
    if (d >= N) return;
    int base = d * R_REL + r0;
    int bsel = min(lane, cc);
    int rp = rowptr[base + bsel];            // lane r in [0,cc]: boundary r
    float iv = inv[base + min(lane, cc - 1)];// lane r in [0,cc-1]: weight of rel r
    int e0 = __shfl(rp, 0);
    int e1 = __shfl(rp, cc);
    int ne = e1 - e0;
    if (ne == 0) return;
    float sum = 0.f;
    for (int rbase = 0; rbase < ne; rbase += 64) {
        int nthis = min(64, ne - rbase);
        int e = e0 + rbase + lane;
        int srcj = (lane < nthis) ? elist[e] : 0;
        int rel = 0;
        for (int r = 1; r <= cc; ++r) rel += (__shfl(rp, r) <= e) ? 1 : 0;
        rel = min(rel, cc - 1);                       // clamp stray lanes
        float wj = __shfl(iv, rel);
        int off = (rel * N + srcj) * HD;              // fits int: < 10*1e5*64
        int j = 0;
        for (; j + 4 <= nthis; j += 4) {
            int o0 = __shfl(off, j), o1 = __shfl(off, j + 1);
            int o2 = __shfl(off, j + 2), o3 = __shfl(off, j + 3);
            float w0 = __shfl(wj, j), w1 = __shfl(wj, j + 1);
            float w2 = __shfl(wj, j + 2), w3 = __shfl(wj, j + 3);
            float v0 = bf16_to_f32(hc[o0 + lane]);
            float v1 = bf16_to_f32(hc[o1 + lane]);
            float v2 = bf16_to_f32(hc[o2 + lane]);
            float v3 = bf16_to_f32(hc[o3 + lane]);
            sum += w0 * v0; sum += w1 * v1; sum += w2 * v2; sum += w3 * v3;
        }
        for (; j < nthis; ++j) {
            int o = __shfl(off, j);
            float ww = __shfl(wj, j);
            sum += ww * bf16_to_f32(hc[o + lane]);
        }
    }
    acc[(size_t)d * HD + lane] += sum;
}

// ---------------- finalize layer 1: relu(acc+b) -> bf16 hi/lo ----------------
__global__ void fin1_kernel(const float* __restrict__ acc, const float* __restrict__ bias,
                            unsigned short* __restrict__ hi, unsigned short* __restrict__ lo,
                            int NH) {
    int i = blockIdx.x * 256 + threadIdx.x;
    if (i < NH) {
        float v = fmaxf(acc[i] + bias[i & (HD - 1)], 0.f);
        unsigned short h = f32_to_bf16_rne(v);
        hi[i] = h;
        lo[i] = f32_to_bf16_rne(v - bf16_to_f32(h));
    }
}

// ---------------- mean pool, fused relu+bias: wave per 256 sorted nodes -------
__global__ __launch_bounds__(256) void pool_kernel(const float* __restrict__ acc,
                                                   const float* __restrict__ bias,
                                                   const int* __restrict__ batch,
                                                   float* __restrict__ pooled,
                                                   float* __restrict__ gcnt, int N) {
    int w = blockIdx.x * 4 + (threadIdx.x >> 6);
    int lane = threadIdx.x & 63;
    int base = w * 256;
    if (base >= N) return;
    float b = bias[lane];
    int cur = -1; float sum = 0.f; int cnt = 0;
    int end = min(base + 256, N);
    for (int n = base; n < end; ++n) {
        int g = batch[n];
        if (g != cur) {
            if (cur >= 0) {
                atomicAdd(&pooled[cur * HD + lane], sum);
                if (lane == 0) atomicAdd(&gcnt[cur], (float)cnt);
            }
            cur = g; sum = 0.f; cnt = 0;
        }
        sum += fmaxf(acc[(size_t)n * HD + lane] + b, 0.f);
        cnt++;
    }
    if (cur >= 0) {
        atomicAdd(&pooled[cur * HD + lane], sum);
        if (lane == 0) atomicAdd(&gcnt[cur], (float)cnt);
    }
}

__global__ void cls_kernel(const float* __restrict__ pooled, const float* __restrict__ gcnt,
                           const float* __restrict__ cls_w, const float* __restrict__ cls_b,
                           float* __restrict__ out) {
    int g = threadIdx.x;   // 64 graphs
    float invc = 1.0f / fmaxf(gcnt[g], 1.0f);
    float acc = 0.f;
    for (int j = 0; j < 64; ++j) acc += pooled[g * 64 + j] * cls_w[j];
    out[g] = acc * invc + cls_b[0];
}

extern "C" void kernel_launch(void* const* d_in, const int* in_sizes, int n_in,
                              void* d_out, int out_size, void* d_ws, size_t ws_size,
                              hipStream_t stream) {
    const float* x     = (const float*)d_in[0];
    const int*   eidx  = (const int*)d_in[1];
    const int*   et    = (const int*)d_in[2];
    const int*   batch = (const int*)d_in[3];
    const float* W1    = (const float*)d_in[4];
    const float* root1 = (const float*)d_in[5];
    const float* b1    = (const float*)d_in[6];
    const float* W2    = (const float*)d_in[7];
    const float* root2 = (const float*)d_in[8];
    const float* b2    = (const float*)d_in[9];
    const float* cls_w = (const float*)d_in[10];
    const float* cls_b = (const float*)d_in[11];

    const int N = in_sizes[3];
    const int E = in_sizes[2];
    const int M = N * R_REL;
    const int NB = (M + 1023) / 1024;
    const int NBK = (N + (1 << BSH) - 1) >> BSH;   // <=512 buckets
    const int* srcp = eidx;
    const int* dstp = eidx + E;

    char* ws = (char*)d_ws;
    size_t off = 0;
    auto alloc = [&](size_t bytes) -> void* {
        void* p = ws + off;
        off = (off + bytes + 255) & ~(size_t)255;
        return p;
    };
    // fixed buffers (~125 MB)
    unsigned short* Xhi  = (unsigned short*)alloc((size_t)N * 128 * 2);   // 25.6 MB
    unsigned short* Xlo  = (unsigned short*)alloc((size_t)N * 128 * 2);   // 25.6 MB
    unsigned short* H1hi = (unsigned short*)alloc((size_t)N * HD * 2);    // 12.8 MB
    unsigned short* H1lo = (unsigned short*)alloc((size_t)N * HD * 2);    // 12.8 MB
    float*          accb = (float*)alloc((size_t)N * HD * 4);             // 25.6 MB
    unsigned short* Wt1hi = (unsigned short*)alloc((size_t)(R_REL + 1) * HD * 128 * 2);
    unsigned short* Wt1lo = (unsigned short*)alloc((size_t)(R_REL + 1) * HD * 128 * 2);
    unsigned short* Wt2hi = (unsigned short*)alloc((size_t)(R_REL + 1) * HD * HD * 2);
    unsigned short* Wt2lo = (unsigned short*)alloc((size_t)(R_REL + 1) * HD * HD * 2);
    int*   keycnt = (int*)alloc((size_t)M * 4);
    int*   rowptr = (int*)alloc((size_t)(M + 1) * 4);
    int*   elist  = (int*)alloc((size_t)E * 4);                           // 12.8 MB
    int*   bsum   = (int*)alloc((size_t)NB * 4);
    int*   bofs   = (int*)alloc((size_t)NB * 4);
    int*   bcnt   = (int*)alloc(512 * 4);
    int*   bboff  = (int*)alloc(513 * 4);
    int*   gcur   = (int*)alloc(512 * 4);
    float* pooled = (float*)alloc((size_t)(64 * HD + 64) * 4);
    float* gcnt   = pooled + 64 * HD;
    float* invf   = (float*)keycnt;

    // staged bucket-grouped (src,key) pairs alias Xhi (+Xlo headroom): consumed
    // by sortfill before split_kernel writes Xhi -- stream-ordered, safe.
    int2* staged = (int2*)Xhi;

    // relation-chunk buffer from whatever workspace remains (12.8 MB per relation)
    size_t per_rel = ((size_t)N * HD * 2 + 255) & ~(size_t)255;
    size_t remain = (ws_size > off) ? (ws_size - off) : 0;
    int C = (int)(remain / per_rel);
    if (C < 1) C = 1;
    if (C > R_REL) C = R_REL;
    unsigned short* h_chunk = (unsigned short*)alloc((size_t)C * per_rel);

    hipMemsetAsync(bcnt, 0, 512 * 4, stream);
    hipMemsetAsync(pooled, 0, (size_t)(64 * HD + 64) * 4, stream);

    // ---- bucketed CSR build ----
    int nchunks = (E + 4095) / 4096;
    bhist_kernel<<<nchunks, 256, 0, stream>>>(dstp, bcnt, E);
    bscan_kernel<<<1, 512, 0, stream>>>(bcnt, bboff, gcur, NBK, E);
    bscatter_kernel<<<nchunks, 256, 0, stream>>>(srcp, dstp, et, gcur, staged, E);
    sortfill_kernel<<<NBK, 256, 0, stream>>>(staged, bboff, keycnt, elist, M);
    scan1_kernel<<<NB, 256, 0, stream>>>(keycnt, bsum, M);
    scan2_kernel<<<1, 1024, 0, stream>>>(bsum, bofs, NB);
    scan3_kernel<<<NB, 256, 0, stream>>>(keycnt, bofs, rowptr, M);
    inv_kernel<<<(M + 255) / 256, 256, 0, stream>>>(keycnt, M);

    // ---- precision-split operands (after staged is dead) ----
    int NK = N * 128;
    split_kernel<<<(NK + 255) / 256, 256, 0, stream>>>(x, Xhi, Xlo, NK);
    int tw1 = (R_REL + 1) * HD * 128, tw2 = (R_REL + 1) * HD * HD;
    wsplit_kernel<<<(tw1 + 255) / 256, 256, 0, stream>>>(W1, root1, Wt1hi, Wt1lo, 128);
    wsplit_kernel<<<(tw2 + 255) / 256, 256, 0, stream>>>(W2, root2, Wt2hi, Wt2lo, HD);

    const int gemmBlocks = (N + 63) / 64;
    const int aggBlocks  = (int)(((size_t)N * 64 + 255) / 256);
    const int NH = N * HD;

    // ---- layer 1 (K=128) ----
    gemm_mfma<128, true><<<gemmBlocks, 256, 0, stream>>>(Xhi, Xlo, Wt1hi, Wt1lo,
                                                         (unsigned short*)nullptr, accb,
                                                         R_REL, 1, N);   // accb = x @ root1
    for (int r0 = 0; r0 < R_REL; r0 += C) {
        int cc = min(C, R_REL - r0);
        gemm_mfma<128, false><<<gemmBlocks, 256, 0, stream>>>(Xhi, Xlo, Wt1hi, Wt1lo,
                                                              h_chunk, (float*)nullptr,
                                                              r0, cc, N);
        agg_chunk_kernel<<<aggBlocks, 256, 0, stream>>>(h_chunk, rowptr, elist, invf,
                                                        accb, N, r0, cc);
    }
    fin1_kernel<<<(NH + 255) / 256, 256, 0, stream>>>(accb, b1, H1hi, H1lo, NH);

    // ---- layer 2 (K=64) ----
    gemm_mfma<64, true><<<gemmBlocks, 256, 0, stream>>>(H1hi, H1lo, Wt2hi, Wt2lo,
                                                        (unsigned short*)nullptr, accb,
                                                        R_REL, 1, N);    // accb = h1 @ root2
    for (int r0 = 0; r0 < R_REL; r0 += C) {
        int cc = min(C, R_REL - r0);
        gemm_mfma<64, false><<<gemmBlocks, 256, 0, stream>>>(H1hi, H1lo, Wt2hi, Wt2lo,
                                                             h_chunk, (float*)nullptr,
                                                             r0, cc, N);
        agg_chunk_kernel<<<aggBlocks, 256, 0, stream>>>(h_chunk, rowptr, elist, invf,
                                                        accb, N, r0, cc);
    }

    // ---- pool (fused relu+bias) + classify ----
    int poolWaves = (N + 255) / 256;
    pool_kernel<<<(poolWaves + 3) / 4, 256, 0, stream>>>(accb, b2, batch, pooled, gcnt, N);
    cls_kernel<<<1, 64, 0, stream>>>(pooled, gcnt, cls_w, cls_b, (float*)d_out);
}

// Round 7
// 750.734 us; speedup vs baseline: 4.1730x; 1.0144x over previous
//
#include <hip/hip_runtime.h>

#define R_REL 10
#define HD 64    // hidden dim, fixed by problem
#define BSH 8    // bucket shift: 256 dst per bucket; N<=131072 -> <=512 buckets
#define KPB (256 * R_REL)   // 2560 keys per bucket
#define SORT_CAP 12288      // LDS edge capacity per bucket (mean 8192, +45 sigma)

typedef __attribute__((ext_vector_type(8))) short short8;
typedef __attribute__((ext_vector_type(4))) float floatx4;
typedef __attribute__((ext_vector_type(8))) unsigned short ushort8;

__device__ inline unsigned short f32_to_bf16_rne(float f) {
    unsigned int u = __float_as_uint(f);
    unsigned int r = (u + 0x7FFFu + ((u >> 16) & 1u)) >> 16;
    return (unsigned short)r;
}
__device__ inline float bf16_to_f32(unsigned short h) {
    return __uint_as_float(((unsigned int)h) << 16);
}

// ================= bucketed CSR build =================
// phase 1: per-bucket edge counts (LDS pre-aggregated), 512 buckets
__global__ __launch_bounds__(256) void bhist_kernel(const int* __restrict__ dst,
                                                    int* __restrict__ bcnt, int E) {
    __shared__ int l[512];
    int t = threadIdx.x;
    l[t] = 0; l[t + 256] = 0;
    __syncthreads();
    int e0 = blockIdx.x * 4096;
    for (int i = t; i < 4096; i += 256) {
        int e = e0 + i;
        if (e < E) atomicAdd(&l[dst[e] >> BSH], 1);
    }
    __syncthreads();
    if (l[t]) atomicAdd(&bcnt[t], l[t]);
    if (l[t + 256]) atomicAdd(&bcnt[t + 256], l[t + 256]);
}

// phase 2: scan 512 bucket counts (single block of 512), init gcursor
__global__ void bscan_kernel(const int* __restrict__ bcnt, int* __restrict__ boff,
                             int* __restrict__ gcursor, int NBK, int E) {
    int t = threadIdx.x;   // 512 threads
    int v = (t < NBK) ? bcnt[t] : 0;
    __shared__ int tmp[512];
    tmp[t] = v;
    __syncthreads();
    for (int off = 1; off < 512; off <<= 1) {
        int u = (t >= off) ? tmp[t - off] : 0;
        __syncthreads();
        tmp[t] += u;
        __syncthreads();
    }
    int excl = tmp[t] - v;
    if (t < NBK) { boff[t] = excl; gcursor[t] = excl; }
    if (t == 0) boff[NBK] = E;
}

// phase 3: scatter edges into bucket-grouped staging, block-local slices
__global__ __launch_bounds__(256) void bscatter_kernel(const int* __restrict__ src,
                                                       const int* __restrict__ dst,
                                                       const int* __restrict__ et,
                                                       int* __restrict__ gcursor,
                                                       int2* __restrict__ staged, int E) {
    __shared__ int lcnt[512];
    __shared__ int lbase[512];
    int t = threadIdx.x;
    int e0 = blockIdx.x * 4096;
    lcnt[t] = 0; lcnt[t + 256] = 0;
    __syncthreads();
    for (int i = t; i < 4096; i += 256) {
        int e = e0 + i;
        if (e < E) atomicAdd(&lcnt[dst[e] >> BSH], 1);
    }
    __syncthreads();
    int c0 = lcnt[t], c1 = lcnt[t + 256];
    lbase[t]       = (c0 > 0) ? atomicAdd(&gcursor[t], c0) : 0;
    lbase[t + 256] = (c1 > 0) ? atomicAdd(&gcursor[t + 256], c1) : 0;
    lcnt[t] = 0; lcnt[t + 256] = 0;
    __syncthreads();
    for (int i = t; i < 4096; i += 256) {
        int e = e0 + i;
        if (e < E) {
            int dd = dst[e];
            int bk = dd >> BSH;
            int pos = lbase[bk] + atomicAdd(&lcnt[bk], 1);
            staged[pos] = make_int2(src[e], dd * R_REL + et[e]);
        }
    }
}

// phase 4: per-bucket LDS counting sort -> coalesced elist + keycnt writes.
// One block per bucket. rowptr[keylo_b] == bboff[b], so no global cursor needed.
__global__ __launch_bounds__(256) void sortfill_kernel(const int2* __restrict__ staged,
                                                       const int* __restrict__ boff,
                                                       int* __restrict__ keycnt,
                                                       int* __restrict__ elist, int M) {
    __shared__ int hist[KPB];       // 10 KB: counts -> exclusive offsets -> cursors
    __shared__ int part[256];       // 1 KB scan partials
    __shared__ int lsrc[SORT_CAP];  // 48 KB sorted src values
    int t = threadIdx.x;
    int b = blockIdx.x;
    int s0 = boff[b], s1 = boff[b + 1];
    int cnt = s1 - s0;
    int keylo = b * KPB;
#pragma unroll
    for (int j = 0; j < KPB / 256; ++j) hist[t + j * 256] = 0;
    __syncthreads();
    // pass 1: histogram
    for (int i = s0 + t; i < s1; i += 256)
        atomicAdd(&hist[staged[i].y - keylo], 1);
    __syncthreads();
    // coalesced keycnt write (replaces global-atomic hist2)
    for (int j = t; j < KPB; j += 256) {
        int k = keylo + j;
        if (k < M) keycnt[k] = hist[j];
    }
    // in-place exclusive scan of hist (each thread owns 10 consecutive keys)
    int base = t * (KPB / 256);
    int c[KPB / 256];
    int s = 0;
#pragma unroll
    for (int j = 0; j < KPB / 256; ++j) { c[j] = hist[base + j]; s += c[j]; }
    part[t] = s;
    __syncthreads();
    for (int off = 1; off < 256; off <<= 1) {
        int u = (t >= off) ? part[t - off] : 0;
        __syncthreads();
        part[t] += u;
        __syncthreads();
    }
    int run = part[t] - s;   // exclusive prefix for this thread's first key
#pragma unroll
    for (int j = 0; j < KPB / 256; ++j) { hist[base + j] = run; run += c[j]; }
    __syncthreads();
    // pass 2: scatter src into LDS at sorted position (hist = running cursor)
    for (int i = s0 + t; i < s1; i += 256) {
        int2 p = staged[i];
        int pos = atomicAdd(&hist[p.y - keylo], 1);
        if (pos < SORT_CAP) lsrc[pos] = p.x;
        else elist[s0 + pos] = p.x;   // overflow fallback (never expected; stays correct)
    }
    __syncthreads();
    // pass 3: coalesced stream-out
    int m = min(cnt, SORT_CAP);
    for (int j = t; j < m; j += 256) elist[s0 + j] = lsrc[j];
}

// ---------------- 3-kernel exclusive scan over M=N*R ints ----------------
__global__ void scan1_kernel(const int* __restrict__ cnt, int* __restrict__ bsum, int M) {
    int b = blockIdx.x, tid = threadIdx.x;
    int base = b * 1024 + tid * 4;
    int s = 0;
#pragma unroll
    for (int j = 0; j < 4; ++j) { int i = base + j; if (i < M) s += cnt[i]; }
    for (int off = 32; off > 0; off >>= 1) s += __shfl_down(s, off);
    __shared__ int wsum[4];
    int lane = tid & 63, wid = tid >> 6;
    if (lane == 0) wsum[wid] = s;
    __syncthreads();
    if (tid == 0) bsum[b] = wsum[0] + wsum[1] + wsum[2] + wsum[3];
}

__global__ void scan2_kernel(const int* __restrict__ bsum, int* __restrict__ boff, int NB) {
    int tid = threadIdx.x;           // 1024 threads
    int lane = tid & 63, wid = tid >> 6;
    int v = (tid < NB) ? bsum[tid] : 0;
    int x = v;
    for (int off = 1; off < 64; off <<= 1) { int u = __shfl_up(x, off); if (lane >= off) x += u; }
    __shared__ int wsum[16];
    if (lane == 63) wsum[wid] = x;
    __syncthreads();
    int woff = 0;
    for (int w = 0; w < wid; ++w) woff += wsum[w];
    if (tid < NB) boff[tid] = x + woff - v;   // exclusive
}

__global__ void scan3_kernel(const int* __restrict__ cnt, const int* __restrict__ boff,
                             int* __restrict__ rowptr, int M) {
    int b = blockIdx.x, tid = threadIdx.x;
    int base = b * 1024 + tid * 4;
    int c[4]; int s = 0;
#pragma unroll
    for (int j = 0; j < 4; ++j) { int i = base + j; c[j] = (i < M) ? cnt[i] : 0; s += c[j]; }
    int lane = tid & 63, wid = tid >> 6;
    int x = s;
    for (int off = 1; off < 64; off <<= 1) { int u = __shfl_up(x, off); if (lane >= off) x += u; }
    __shared__ int wsum[4];
    if (lane == 63) wsum[wid] = x;
    __syncthreads();
    int woff = 0;
    for (int w = 0; w < wid; ++w) woff += wsum[w];
    int run = boff[b] + x + woff - s;        // exclusive start for this thread
#pragma unroll
    for (int j = 0; j < 4; ++j) {
        int i = base + j;
        if (i < M) {
            rowptr[i] = run; run += c[j];
            if (i == M - 1) rowptr[M] = run;
        }
    }
}

// in-place: read int count, write float 1/max(cnt,1) into same buffer
__global__ void inv_kernel(int* __restrict__ cnt, int M) {
    int i = blockIdx.x * 256 + threadIdx.x;
    if (i < M) {
        float c = (float)cnt[i];
        ((float*)cnt)[i] = 1.0f / fmaxf(c, 1.0f);
    }
}

// ---------------- hi/lo bf16 split of a f32 array ----------------
__global__ void split_kernel(const float* __restrict__ src, unsigned short* __restrict__ hi,
                             unsigned short* __restrict__ lo, int n) {
    int i = blockIdx.x * 256 + threadIdx.x;
    if (i < n) {
        float v = src[i];
        unsigned short h = f32_to_bf16_rne(v);
        hi[i] = h;
        lo[i] = f32_to_bf16_rne(v - bf16_to_f32(h));
    }
}

// W [R][K][HD] + root [K][HD] f32  ->  Wt hi/lo bf16 [(R+1)][HD][K]  (n-major, k contiguous)
__global__ void wsplit_kernel(const float* __restrict__ W, const float* __restrict__ root,
                              unsigned short* __restrict__ hi, unsigned short* __restrict__ lo,
                              int K) {
    int idx = blockIdx.x * 256 + threadIdx.x;
    int total = (R_REL + 1) * HD * K;
    if (idx >= total) return;
    int rel = idx / (HD * K);
    int rem = idx - rel * HD * K;
    int n = rem / K, k = rem - n * K;
    float v = (rel < R_REL) ? W[((size_t)rel * K + k) * HD + n] : root[(size_t)k * HD + n];
    unsigned short h = f32_to_bf16_rne(v);
    hi[idx] = h;
    lo[idx] = f32_to_bf16_rne(v - bf16_to_f32(h));
}

// ---------------- MFMA GEMM: per block 64 nodes x 64 outs, nrel relations ----
// A-fragments (relation-invariant) are hoisted into registers ONCE, then the
// relation loop is {B loads (L2-hot), 48 MFMA, stores} -- zero LDS traffic.
// __launch_bounds__(256,2): allow 256 VGPRs (A-frags = 128 VGPRs at K=128).
template <int K, bool F32OUT>
__global__ __launch_bounds__(256, 2) void gemm_mfma(const unsigned short* __restrict__ Xhi,
                                                    const unsigned short* __restrict__ Xlo,
                                                    const unsigned short* __restrict__ Wthi,
                                                    const unsigned short* __restrict__ Wtlo,
                                                    unsigned short* __restrict__ hout,
                                                    float* __restrict__ fout,
                                                    int r0, int nrel, int N) {
    constexpr int LDK = K + 8;
    constexpr int NS = K / 32;
    __shared__ unsigned short xs_hi[64 * LDK];
    __shared__ unsigned short xs_lo[64 * LDK];
    const int tid = threadIdx.x;
    const int w = tid >> 6, lane = tid & 63;
    const int n0 = blockIdx.x * 64;
    constexpr int CH = K / 8;          // 16B chunks per row
    constexpr int RPI = 256 / CH;      // rows staged per iteration
#pragma unroll
    for (int it = 0; it < 64 / RPI; ++it) {
        int row = it * RPI + tid / CH;
        int ck = (tid & (CH - 1)) * 8;
        int node = n0 + row;
        ushort8 vh, vl;
#pragma unroll
        for (int q = 0; q < 8; ++q) { vh[q] = 0; vl[q] = 0; }
        if (node < N) {
            vh = *(const ushort8*)(Xhi + (size_t)node * K + ck);
            vl = *(const ushort8*)(Xlo + (size_t)node * K + ck);
        }
        *(ushort8*)&xs_hi[row * LDK + ck] = vh;
        *(ushort8*)&xs_lo[row * LDK + ck] = vl;
    }
    __syncthreads();
    const int quad = lane >> 4, l16 = lane & 15;
    const int colg = w * 16 + l16;
    // hoist A-fragments to registers (once; reused for all relations)
    short8 Ah[4][NS], Al[4][NS];
#pragma unroll
    for (int mt = 0; mt < 4; ++mt) {
#pragma unroll
        for (int s = 0; s < NS; ++s) {
            int ko = s * 32 + quad * 8;
            Ah[mt][s] = *(const short8*)&xs_hi[(mt * 16 + l16) * LDK + ko];
            Al[mt][s] = *(const short8*)&xs_lo[(mt * 16 + l16) * LDK + ko];
        }
    }
    for (int c = 0; c < nrel; ++c) {
        int rel = r0 + c;
        const unsigned short* bh_base = Wthi + ((size_t)rel * HD + colg) * K + quad * 8;
        const unsigned short* bl_base = Wtlo + ((size_t)rel * HD + colg) * K + quad * 8;
        floatx4 zero = {0.f, 0.f, 0.f, 0.f};
        floatx4 acc[4];
#pragma unroll
        for (int mt = 0; mt < 4; ++mt) acc[mt] = zero;
#pragma unroll
        for (int s = 0; s < NS; ++s) {
            short8 bh = *(const short8*)(bh_base + s * 32);
            short8 bl = *(const short8*)(bl_base + s * 32);
#pragma unroll
            for (int mt = 0; mt < 4; ++mt) {
                acc[mt] = __builtin_amdgcn_mfma_f32_16x16x32_bf16(Ah[mt][s], bh, acc[mt], 0, 0, 0);
                acc[mt] = __builtin_amdgcn_mfma_f32_16x16x32_bf16(Al[mt][s], bh, acc[mt], 0, 0, 0);
                acc[mt] = __builtin_amdgcn_mfma_f32_16x16x32_bf16(Ah[mt][s], bl, acc[mt], 0, 0, 0);
            }
        }
        // C/D layout: col = lane&15, row = quad*4 + reg  [HW-verified]
#pragma unroll
        for (int mt = 0; mt < 4; ++mt) {
#pragma unroll
            for (int r = 0; r < 4; ++r) {
                int node = n0 + mt * 16 + quad * 4 + r;
                if (node < N) {
                    if (F32OUT)
                        fout[(size_t)node * HD + colg] = acc[mt][r];
                    else
                        hout[(size_t)c * N * HD + (size_t)node * HD + colg] =
                            f32_to_bf16_rne(acc[mt][r]);
                }
            }
        }
    }
}

// ---------------- cooperative chunked aggregation: one wave per dst ----------
__global__ __launch_bounds__(256) void agg_chunk_kernel(const unsigned short* __restrict__ hc,
                                                        const int* __restrict__ rowptr,
                                                        const int* __restrict__ elist,
                                                        const float* __restrict__ inv,
                                                        float* __restrict__ acc,
                                                        int N, int r0, int cc) {
    int gid = blockIdx.x * 256 + threadIdx.x;
    int d = gid >> 6;
    int lane = threadIdx.x & 63;
    if (d >= N) return;
    int base = d * R_REL + r0;
    int bsel = min(lane, cc);
    int rp = rowptr[base + bsel];            // lane r in [0,cc]: boundary r
    float iv = inv[base + min(lane, cc - 1)];// lane r in [0,cc-1]: weight of rel r
    int e0 = __shfl(rp, 0);
    int e1 = __shfl(rp, cc);
    int ne = e1 - e0;
    if (ne == 0) return;
    float sum = 0.f;
    for (int rbase = 0; rbase < ne; rbase += 64) {
        int nthis = min(64, ne - rbase);
        int e = e0 + rbase + lane;
        int srcj = (lane < nthis) ? elist[e] : 0;
        int rel = 0;
        for (int r = 1; r <= cc; ++r) rel += (__shfl(rp, r) <= e) ? 1 : 0;
        rel = min(rel, cc - 1);                       // clamp stray lanes
        float wj = __shfl(iv, rel);
        int off = (rel * N + srcj) * HD;              // fits int: < 10*1e5*64
        int j = 0;
        for (; j + 4 <= nthis; j += 4) {
            int o0 = __shfl(off, j), o1 = __shfl(off, j + 1);
            int o2 = __shfl(off, j + 2), o3 = __shfl(off, j + 3);
            float w0 = __shfl(wj, j), w1 = __shfl(wj, j + 1);
            float w2 = __shfl(wj, j + 2), w3 = __shfl(wj, j + 3);
            float v0 = bf16_to_f32(hc[o0 + lane]);
            float v1 = bf16_to_f32(hc[o1 + lane]);
            float v2 = bf16_to_f32(hc[o2 + lane]);
            float v3 = bf16_to_f32(hc[o3 + lane]);
            sum += w0 * v0; sum += w1 * v1; sum += w2 * v2; sum += w3 * v3;
        }
        for (; j < nthis; ++j) {
            int o = __shfl(off, j);
            float ww = __shfl(wj, j);
            sum += ww * bf16_to_f32(hc[o + lane]);
        }
    }
    acc[(size_t)d * HD + lane] += sum;
}

// ---------------- finalize layer 1: relu(acc+b) -> bf16 hi/lo ----------------
__global__ void fin1_kernel(const float* __restrict__ acc, const float* __restrict__ bias,
                            unsigned short* __restrict__ hi, unsigned short* __restrict__ lo,
                            int NH) {
    int i = blockIdx.x * 256 + threadIdx.x;
    if (i < NH) {
        float v = fmaxf(acc[i] + bias[i & (HD - 1)], 0.f);
        unsigned short h = f32_to_bf16_rne(v);
        hi[i] = h;
        lo[i] = f32_to_bf16_rne(v - bf16_to_f32(h));
    }
}

// ---------------- mean pool, fused relu+bias: wave per 256 sorted nodes -------
__global__ __launch_bounds__(256) void pool_kernel(const float* __restrict__ acc,
                                                   const float* __restrict__ bias,
                                                   const int* __restrict__ batch,
                                                   float* __restrict__ pooled,
                                                   float* __restrict__ gcnt, int N) {
    int w = blockIdx.x * 4 + (threadIdx.x >> 6);
    int lane = threadIdx.x & 63;
    int base = w * 256;
    if (base >= N) return;
    float b = bias[lane];
    int cur = -1; float sum = 0.f; int cnt = 0;
    int end = min(base + 256, N);
    for (int n = base; n < end; ++n) {
        int g = batch[n];
        if (g != cur) {
            if (cur >= 0) {
                atomicAdd(&pooled[cur * HD + lane], sum);
                if (lane == 0) atomicAdd(&gcnt[cur], (float)cnt);
            }
            cur = g; sum = 0.f; cnt = 0;
        }
        sum += fmaxf(acc[(size_t)n * HD + lane] + b, 0.f);
        cnt++;
    }
    if (cur >= 0) {
        atomicAdd(&pooled[cur * HD + lane], sum);
        if (lane == 0) atomicAdd(&gcnt[cur], (float)cnt);
    }
}

__global__ void cls_kernel(const float* __restrict__ pooled, const float* __restrict__ gcnt,
                           const float* __restrict__ cls_w, const float* __restrict__ cls_b,
                           float* __restrict__ out) {
    int g = threadIdx.x;   // 64 graphs
    float invc = 1.0f / fmaxf(gcnt[g], 1.0f);
    float acc = 0.f;
    for (int j = 0; j < 64; ++j) acc += pooled[g * 64 + j] * cls_w[j];
    out[g] = acc * invc + cls_b[0];
}

extern "C" void kernel_launch(void* const* d_in, const int* in_sizes, int n_in,
                              void* d_out, int out_size, void* d_ws, size_t ws_size,
                              hipStream_t stream) {
    const float* x     = (const float*)d_in[0];
    const int*   eidx  = (const int*)d_in[1];
    const int*   et    = (const int*)d_in[2];
    const int*   batch = (const int*)d_in[3];
    const float* W1    = (const float*)d_in[4];
    const float* root1 = (const float*)d_in[5];
    const float* b1    = (const float*)d_in[6];
    const float* W2    = (const float*)d_in[7];
    const float* root2 = (const float*)d_in[8];
    const float* b2    = (const float*)d_in[9];
    const float* cls_w = (const float*)d_in[10];
    const float* cls_b = (const float*)d_in[11];

    const int N = in_sizes[3];
    const int E = in_sizes[2];
    const int M = N * R_REL;
    const int NB = (M + 1023) / 1024;
    const int NBK = (N + (1 << BSH) - 1) >> BSH;   // <=512 buckets
    const int* srcp = eidx;
    const int* dstp = eidx + E;

    char* ws = (char*)d_ws;
    size_t off = 0;
    auto alloc = [&](size_t bytes) -> void* {
        void* p = ws + off;
        off = (off + bytes + 255) & ~(size_t)255;
        return p;
    };
    // fixed buffers (~125 MB)
    unsigned short* Xhi  = (unsigned short*)alloc((size_t)N * 128 * 2);   // 25.6 MB
    unsigned short* Xlo  = (unsigned short*)alloc((size_t)N * 128 * 2);   // 25.6 MB
    unsigned short* H1hi = (unsigned short*)alloc((size_t)N * HD * 2);    // 12.8 MB
    unsigned short* H1lo = (unsigned short*)alloc((size_t)N * HD * 2);    // 12.8 MB
    float*          accb = (float*)alloc((size_t)N * HD * 4);             // 25.6 MB
    unsigned short* Wt1hi = (unsigned short*)alloc((size_t)(R_REL + 1) * HD * 128 * 2);
    unsigned short* Wt1lo = (unsigned short*)alloc((size_t)(R_REL + 1) * HD * 128 * 2);
    unsigned short* Wt2hi = (unsigned short*)alloc((size_t)(R_REL + 1) * HD * HD * 2);
    unsigned short* Wt2lo = (unsigned short*)alloc((size_t)(R_REL + 1) * HD * HD * 2);
    int*   keycnt = (int*)alloc((size_t)M * 4);
    int*   rowptr = (int*)alloc((size_t)(M + 1) * 4);
    int*   elist  = (int*)alloc((size_t)E * 4);                           // 12.8 MB
    int*   bsum   = (int*)alloc((size_t)NB * 4);
    int*   bofs   = (int*)alloc((size_t)NB * 4);
    int*   bcnt   = (int*)alloc(512 * 4);
    int*   bboff  = (int*)alloc(513 * 4);
    int*   gcur   = (int*)alloc(512 * 4);
    float* pooled = (float*)alloc((size_t)(64 * HD + 64) * 4);
    float* gcnt   = pooled + 64 * HD;
    float* invf   = (float*)keycnt;

    // staged bucket-grouped (src,key) pairs alias Xhi (+Xlo headroom): consumed
    // by sortfill before split_kernel writes Xhi -- stream-ordered, safe.
    int2* staged = (int2*)Xhi;

    // relation-chunk buffer from whatever workspace remains (12.8 MB per relation)
    size_t per_rel = ((size_t)N * HD * 2 + 255) & ~(size_t)255;
    size_t remain = (ws_size > off) ? (ws_size - off) : 0;
    int C = (int)(remain / per_rel);
    if (C < 1) C = 1;
    if (C > R_REL) C = R_REL;
    unsigned short* h_chunk = (unsigned short*)alloc((size_t)C * per_rel);

    hipMemsetAsync(bcnt, 0, 512 * 4, stream);
    hipMemsetAsync(pooled, 0, (size_t)(64 * HD + 64) * 4, stream);

    // ---- bucketed CSR build ----
    int nchunks = (E + 4095) / 4096;
    bhist_kernel<<<nchunks, 256, 0, stream>>>(dstp, bcnt, E);
    bscan_kernel<<<1, 512, 0, stream>>>(bcnt, bboff, gcur, NBK, E);
    bscatter_kernel<<<nchunks, 256, 0, stream>>>(srcp, dstp, et, gcur, staged, E);
    sortfill_kernel<<<NBK, 256, 0, stream>>>(staged, bboff, keycnt, elist, M);
    scan1_kernel<<<NB, 256, 0, stream>>>(keycnt, bsum, M);
    scan2_kernel<<<1, 1024, 0, stream>>>(bsum, bofs, NB);
    scan3_kernel<<<NB, 256, 0, stream>>>(keycnt, bofs, rowptr, M);
    inv_kernel<<<(M + 255) / 256, 256, 0, stream>>>(keycnt, M);

    // ---- precision-split operands (after staged is dead) ----
    int NK = N * 128;
    split_kernel<<<(NK + 255) / 256, 256, 0, stream>>>(x, Xhi, Xlo, NK);
    int tw1 = (R_REL + 1) * HD * 128, tw2 = (R_REL + 1) * HD * HD;
    wsplit_kernel<<<(tw1 + 255) / 256, 256, 0, stream>>>(W1, root1, Wt1hi, Wt1lo, 128);
    wsplit_kernel<<<(tw2 + 255) / 256, 256, 0, stream>>>(W2, root2, Wt2hi, Wt2lo, HD);

    const int gemmBlocks = (N + 63) / 64;
    const int aggBlocks  = (int)(((size_t)N * 64 + 255) / 256);
    const int NH = N * HD;

    // ---- layer 1 (K=128) ----
    gemm_mfma<128, true><<<gemmBlocks, 256, 0, stream>>>(Xhi, Xlo, Wt1hi, Wt1lo,
                                                         (unsigned short*)nullptr, accb,
                                                         R_REL, 1, N);   // accb = x @ root1
    for (int r0 = 0; r0 < R_REL; r0 += C) {
        int cc = min(C, R_REL - r0);
        gemm_mfma<128, false><<<gemmBlocks, 256, 0, stream>>>(Xhi, Xlo, Wt1hi, Wt1lo,
                                                              h_chunk, (float*)nullptr,
                                                              r0, cc, N);
        agg_chunk_kernel<<<aggBlocks, 256, 0, stream>>>(h_chunk, rowptr, elist, invf,
                                                        accb, N, r0, cc);
    }
    fin1_kernel<<<(NH + 255) / 256, 256, 0, stream>>>(accb, b1, H1hi, H1lo, NH);

    // ---- layer 2 (K=64) ----
    gemm_mfma<64, true><<<gemmBlocks, 256, 0, stream>>>(H1hi, H1lo, Wt2hi, Wt2lo,
                                                        (unsigned short*)nullptr, accb,
                                                        R_REL, 1, N);    // accb = h1 @ root2
    for (int r0 = 0; r0 < R_REL; r0 += C) {
        int cc = min(C, R_REL - r0);
        gemm_mfma<64, false><<<gemmBlocks, 256, 0, stream>>>(H1hi, H1lo, Wt2hi, Wt2lo,
                                                             h_chunk, (float*)nullptr,
                                                             r0, cc, N);
        agg_chunk_kernel<<<aggBlocks, 256, 0, stream>>>(h_chunk, rowptr, elist, invf,
                                                        accb, N, r0, cc);
    }

    // ---- pool (fused relu+bias) + classify ----
    int poolWaves = (N + 255) / 256;
    pool_kernel<<<(poolWaves + 3) / 4, 256, 0, stream>>>(accb, b2, batch, pooled, gcnt, N);
    cls_kernel<<<1, 64, 0, stream>>>(pooled, gcnt, cls_w, cls_b, (float*)d_out);
}

// Round 8
// 732.053 us; speedup vs baseline: 4.2795x; 1.0255x over previous
//
#include <hip/hip_runtime.h>

#define R_REL 10
#define HD 64    // hidden dim, fixed by problem
#define BSH 8    // bucket shift: 256 dst per bucket; N<=131072 -> <=512 buckets
#define KPB (256 * R_REL)   // 2560 keys per bucket
#define SORT_CAP 12288      // LDS edge capacity per bucket (mean 8192, +45 sigma)

typedef __attribute__((ext_vector_type(8))) short short8;
typedef __attribute__((ext_vector_type(4))) float floatx4;
typedef __attribute__((ext_vector_type(8))) unsigned short ushort8;

__device__ inline unsigned short f32_to_bf16_rne(float f) {
    unsigned int u = __float_as_uint(f);
    unsigned int r = (u + 0x7FFFu + ((u >> 16) & 1u)) >> 16;
    return (unsigned short)r;
}
__device__ inline float bf16_to_f32(unsigned short h) {
    return __uint_as_float(((unsigned int)h) << 16);
}
__device__ inline float bf16lo(unsigned int u) { return __uint_as_float(u << 16); }
__device__ inline float bf16hi(unsigned int u) { return __uint_as_float(u & 0xFFFF0000u); }

// ================= bucketed CSR build =================
__global__ __launch_bounds__(256) void bhist_kernel(const int* __restrict__ dst,
                                                    int* __restrict__ bcnt, int E) {
    __shared__ int l[512];
    int t = threadIdx.x;
    l[t] = 0; l[t + 256] = 0;
    __syncthreads();
    int e0 = blockIdx.x * 4096;
    for (int i = t; i < 4096; i += 256) {
        int e = e0 + i;
        if (e < E) atomicAdd(&l[dst[e] >> BSH], 1);
    }
    __syncthreads();
    if (l[t]) atomicAdd(&bcnt[t], l[t]);
    if (l[t + 256]) atomicAdd(&bcnt[t + 256], l[t + 256]);
}

__global__ void bscan_kernel(const int* __restrict__ bcnt, int* __restrict__ boff,
                             int* __restrict__ gcursor, int NBK, int E) {
    int t = threadIdx.x;   // 512 threads
    int v = (t < NBK) ? bcnt[t] : 0;
    __shared__ int tmp[512];
    tmp[t] = v;
    __syncthreads();
    for (int off = 1; off < 512; off <<= 1) {
        int u = (t >= off) ? tmp[t - off] : 0;
        __syncthreads();
        tmp[t] += u;
        __syncthreads();
    }
    int excl = tmp[t] - v;
    if (t < NBK) { boff[t] = excl; gcursor[t] = excl; }
    if (t == 0) boff[NBK] = E;
}

__global__ __launch_bounds__(256) void bscatter_kernel(const int* __restrict__ src,
                                                       const int* __restrict__ dst,
                                                       const int* __restrict__ et,
                                                       int* __restrict__ gcursor,
                                                       int2* __restrict__ staged, int E) {
    __shared__ int lcnt[512];
    __shared__ int lbase[512];
    int t = threadIdx.x;
    int e0 = blockIdx.x * 4096;
    lcnt[t] = 0; lcnt[t + 256] = 0;
    __syncthreads();
    for (int i = t; i < 4096; i += 256) {
        int e = e0 + i;
        if (e < E) atomicAdd(&lcnt[dst[e] >> BSH], 1);
    }
    __syncthreads();
    int c0 = lcnt[t], c1 = lcnt[t + 256];
    lbase[t]       = (c0 > 0) ? atomicAdd(&gcursor[t], c0) : 0;
    lbase[t + 256] = (c1 > 0) ? atomicAdd(&gcursor[t + 256], c1) : 0;
    lcnt[t] = 0; lcnt[t + 256] = 0;
    __syncthreads();
    for (int i = t; i < 4096; i += 256) {
        int e = e0 + i;
        if (e < E) {
            int dd = dst[e];
            int bk = dd >> BSH;
            int pos = lbase[bk] + atomicAdd(&lcnt[bk], 1);
            staged[pos] = make_int2(src[e], dd * R_REL + et[e]);
        }
    }
}

// per-bucket LDS counting sort -> coalesced edata {rel*N+src, weight} + dcnt.
// thread t owns local dst t (10 consecutive keys). rowptr[dst0_b] == bboff[b].
__global__ __launch_bounds__(256) void sortfill_kernel(const int2* __restrict__ staged,
                                                       const int* __restrict__ boff,
                                                       int* __restrict__ dcnt,
                                                       int2* __restrict__ edata,
                                                       int N, int Ntot) {
    __shared__ int hist[KPB];                 // 10 KB: counts -> cursors
    __shared__ float wkey[KPB];               // 10 KB: per-key weight 1/cnt
    __shared__ int part[256];                 // 1 KB
    __shared__ int lsrc[SORT_CAP];            // 48 KB
    __shared__ unsigned short lkey[SORT_CAP]; // 24 KB
    int t = threadIdx.x, b = blockIdx.x;
    int s0 = boff[b], s1 = boff[b + 1];
    int keylo = b * KPB;
#pragma unroll
    for (int j = 0; j < KPB / 256; ++j) hist[t + j * 256] = 0;
    __syncthreads();
    for (int i = s0 + t; i < s1; i += 256)
        atomicAdd(&hist[staged[i].y - keylo], 1);
    __syncthreads();
    // per-local-dst totals + per-key weights; exclusive scan
    int base = t * (KPB / 256);
    int c[KPB / 256];
    int s = 0;
#pragma unroll
    for (int j = 0; j < KPB / 256; ++j) {
        c[j] = hist[base + j]; s += c[j];
        wkey[base + j] = 1.0f / fmaxf((float)c[j], 1.0f);
    }
    int dglob = b * 256 + t;
    if (dglob < Ntot) dcnt[dglob] = s;
    part[t] = s;
    __syncthreads();
    for (int off = 1; off < 256; off <<= 1) {
        int u = (t >= off) ? part[t - off] : 0;
        __syncthreads();
        part[t] += u;
        __syncthreads();
    }
    int run = part[t] - s;
#pragma unroll
    for (int j = 0; j < KPB / 256; ++j) { hist[base + j] = run; run += c[j]; }
    __syncthreads();
    // scatter into LDS at sorted position
    for (int i = s0 + t; i < s1; i += 256) {
        int2 p = staged[i];
        int lk = p.y - keylo;
        int pos = atomicAdd(&hist[lk], 1);
        if (pos < SORT_CAP) { lsrc[pos] = p.x; lkey[pos] = (unsigned short)lk; }
        else {  // overflow fallback (never expected; stays correct)
            int rel = lk % R_REL;
            edata[s0 + pos] = make_int2(rel * N + p.x, __float_as_int(wkey[lk]));
        }
    }
    __syncthreads();
    // coalesced stream-out
    int m = min(s1 - s0, SORT_CAP);
    for (int j = t; j < m; j += 256) {
        int lk = lkey[j];
        int rel = lk % R_REL;
        edata[s0 + j] = make_int2(rel * N + lsrc[j], __float_as_int(wkey[lk]));
    }
}

// ---------------- 3-kernel exclusive scan over N ints ----------------
__global__ void scan1_kernel(const int* __restrict__ cnt, int* __restrict__ bsum, int M) {
    int b = blockIdx.x, tid = threadIdx.x;
    int base = b * 1024 + tid * 4;
    int s = 0;
#pragma unroll
    for (int j = 0; j < 4; ++j) { int i = base + j; if (i < M) s += cnt[i]; }
    for (int off = 32; off > 0; off >>= 1) s += __shfl_down(s, off);
    __shared__ int wsum[4];
    int lane = tid & 63, wid = tid >> 6;
    if (lane == 0) wsum[wid] = s;
    __syncthreads();
    if (tid == 0) bsum[b] = wsum[0] + wsum[1] + wsum[2] + wsum[3];
}

__global__ void scan2_kernel(const int* __restrict__ bsum, int* __restrict__ boff, int NB) {
    int tid = threadIdx.x;           // 1024 threads
    int lane = tid & 63, wid = tid >> 6;
    int v = (tid < NB) ? bsum[tid] : 0;
    int x = v;
    for (int off = 1; off < 64; off <<= 1) { int u = __shfl_up(x, off); if (lane >= off) x += u; }
    __shared__ int wsum[16];
    if (lane == 63) wsum[wid] = x;
    __syncthreads();
    int woff = 0;
    for (int w = 0; w < wid; ++w) woff += wsum[w];
    if (tid < NB) boff[tid] = x + woff - v;   // exclusive
}

__global__ void scan3_kernel(const int* __restrict__ cnt, const int* __restrict__ boff,
                             int* __restrict__ rowptr, int M) {
    int b = blockIdx.x, tid = threadIdx.x;
    int base = b * 1024 + tid * 4;
    int c[4]; int s = 0;
#pragma unroll
    for (int j = 0; j < 4; ++j) { int i = base + j; c[j] = (i < M) ? cnt[i] : 0; s += c[j]; }
    int lane = tid & 63, wid = tid >> 6;
    int x = s;
    for (int off = 1; off < 64; off <<= 1) { int u = __shfl_up(x, off); if (lane >= off) x += u; }
    __shared__ int wsum[4];
    if (lane == 63) wsum[wid] = x;
    __syncthreads();
    int woff = 0;
    for (int w = 0; w < wid; ++w) woff += wsum[w];
    int run = boff[b] + x + woff - s;
#pragma unroll
    for (int j = 0; j < 4; ++j) {
        int i = base + j;
        if (i < M) {
            rowptr[i] = run; run += c[j];
            if (i == M - 1) rowptr[M] = run;
        }
    }
}

// ---------------- hi/lo bf16 split of a f32 array ----------------
__global__ void split_kernel(const float* __restrict__ src, unsigned short* __restrict__ hi,
                             unsigned short* __restrict__ lo, int n) {
    int i = blockIdx.x * 256 + threadIdx.x;
    if (i < n) {
        float v = src[i];
        unsigned short h = f32_to_bf16_rne(v);
        hi[i] = h;
        lo[i] = f32_to_bf16_rne(v - bf16_to_f32(h));
    }
}

// W [R][K][HD] + root [K][HD] f32  ->  Wt hi/lo bf16 [(R+1)][HD][K]
__global__ void wsplit_kernel(const float* __restrict__ W, const float* __restrict__ root,
                              unsigned short* __restrict__ hi, unsigned short* __restrict__ lo,
                              int K) {
    int idx = blockIdx.x * 256 + threadIdx.x;
    int total = (R_REL + 1) * HD * K;
    if (idx >= total) return;
    int rel = idx / (HD * K);
    int rem = idx - rel * HD * K;
    int n = rem / K, k = rem - n * K;
    float v = (rel < R_REL) ? W[((size_t)rel * K + k) * HD + n] : root[(size_t)k * HD + n];
    unsigned short h = f32_to_bf16_rne(v);
    hi[idx] = h;
    lo[idx] = f32_to_bf16_rne(v - bf16_to_f32(h));
}

// ---------------- MFMA GEMM: per block 64 nodes x 64 outs, nrel relations ----
template <int K, bool F32OUT>
__global__ __launch_bounds__(256, 2) void gemm_mfma(const unsigned short* __restrict__ Xhi,
                                                    const unsigned short* __restrict__ Xlo,
                                                    const unsigned short* __restrict__ Wthi,
                                                    const unsigned short* __restrict__ Wtlo,
                                                    unsigned short* __restrict__ hout,
                                                    float* __restrict__ fout,
                                                    int r0, int nrel, int N) {
    constexpr int LDK = K + 8;
    constexpr int NS = K / 32;
    __shared__ unsigned short xs_hi[64 * LDK];
    __shared__ unsigned short xs_lo[64 * LDK];
    const int tid = threadIdx.x;
    const int w = tid >> 6, lane = tid & 63;
    const int n0 = blockIdx.x * 64;
    constexpr int CH = K / 8;
    constexpr int RPI = 256 / CH;
#pragma unroll
    for (int it = 0; it < 64 / RPI; ++it) {
        int row = it * RPI + tid / CH;
        int ck = (tid & (CH - 1)) * 8;
        int node = n0 + row;
        ushort8 vh, vl;
#pragma unroll
        for (int q = 0; q < 8; ++q) { vh[q] = 0; vl[q] = 0; }
        if (node < N) {
            vh = *(const ushort8*)(Xhi + (size_t)node * K + ck);
            vl = *(const ushort8*)(Xlo + (size_t)node * K + ck);
        }
        *(ushort8*)&xs_hi[row * LDK + ck] = vh;
        *(ushort8*)&xs_lo[row * LDK + ck] = vl;
    }
    __syncthreads();
    const int quad = lane >> 4, l16 = lane & 15;
    const int colg = w * 16 + l16;
    short8 Ah[4][NS], Al[4][NS];
#pragma unroll
    for (int mt = 0; mt < 4; ++mt) {
#pragma unroll
        for (int s = 0; s < NS; ++s) {
            int ko = s * 32 + quad * 8;
            Ah[mt][s] = *(const short8*)&xs_hi[(mt * 16 + l16) * LDK + ko];
            Al[mt][s] = *(const short8*)&xs_lo[(mt * 16 + l16) * LDK + ko];
        }
    }
    for (int c = 0; c < nrel; ++c) {
        int rel = r0 + c;
        const unsigned short* bh_base = Wthi + ((size_t)rel * HD + colg) * K + quad * 8;
        const unsigned short* bl_base = Wtlo + ((size_t)rel * HD + colg) * K + quad * 8;
        floatx4 zero = {0.f, 0.f, 0.f, 0.f};
        floatx4 acc[4];
#pragma unroll
        for (int mt = 0; mt < 4; ++mt) acc[mt] = zero;
#pragma unroll
        for (int s = 0; s < NS; ++s) {
            short8 bh = *(const short8*)(bh_base + s * 32);
            short8 bl = *(const short8*)(bl_base + s * 32);
#pragma unroll
            for (int mt = 0; mt < 4; ++mt) {
                acc[mt] = __builtin_amdgcn_mfma_f32_16x16x32_bf16(Ah[mt][s], bh, acc[mt], 0, 0, 0);
                acc[mt] = __builtin_amdgcn_mfma_f32_16x16x32_bf16(Al[mt][s], bh, acc[mt], 0, 0, 0);
                acc[mt] = __builtin_amdgcn_mfma_f32_16x16x32_bf16(Ah[mt][s], bl, acc[mt], 0, 0, 0);
            }
        }
        // C/D layout: col = lane&15, row = quad*4 + reg  [HW-verified]
#pragma unroll
        for (int mt = 0; mt < 4; ++mt) {
#pragma unroll
            for (int r = 0; r < 4; ++r) {
                int node = n0 + mt * 16 + quad * 4 + r;
                if (node < N) {
                    if (F32OUT)
                        fout[(size_t)node * HD + colg] = acc[mt][r];
                    else
                        hout[(size_t)c * N * HD + (size_t)node * HD + colg] =
                            f32_to_bf16_rne(acc[mt][r]);
                }
            }
        }
    }
}

// ---------------- aggregation v3: wave per dst, 4 edges in flight ------------
// 16 lanes x 8B cover one 128B row; quarter = lane>>4 selects the edge.
// edata[e] = {rel*N+src, weight}; pad lanes carry weight 0 (uniform loop).
__global__ __launch_bounds__(256) void agg_kernel(const unsigned short* __restrict__ hc,
                                                  const int* __restrict__ rowptr,
                                                  const int2* __restrict__ edata,
                                                  float* __restrict__ acc, int N) {
    int gid = blockIdx.x * 256 + threadIdx.x;
    int d = gid >> 6;
    if (d >= N) return;
    int lane = threadIdx.x & 63;
    int quarter = lane >> 4, l16 = lane & 15;
    int e0 = rowptr[d], e1 = rowptr[d + 1];
    int ne = e1 - e0;
    if (ne == 0) return;
    float s0 = 0.f, s1 = 0.f, s2 = 0.f, s3 = 0.f;
    for (int rb = 0; rb < ne; rb += 64) {
        int nthis = min(64, ne - rb);
        int2 ed = make_int2(0, 0);
        if (lane < nthis) ed = edata[e0 + rb + lane];
        int off = ed.x << 6;                    // * HD
        float wv = __int_as_float(ed.y);        // 0 for pad lanes
        for (int j = 0; j < nthis; j += 8) {
            int   oa = __shfl(off, j + quarter);
            float wa = __shfl(wv,  j + quarter);
            int   ob = __shfl(off, j + 4 + quarter);
            float wb = __shfl(wv,  j + 4 + quarter);
            uint2 da = *(const uint2*)(hc + oa + l16 * 4);
            uint2 db = *(const uint2*)(hc + ob + l16 * 4);
            s0 += wa * bf16lo(da.x); s1 += wa * bf16hi(da.x);
            s2 += wa * bf16lo(da.y); s3 += wa * bf16hi(da.y);
            s0 += wb * bf16lo(db.x); s1 += wb * bf16hi(db.x);
            s2 += wb * bf16lo(db.y); s3 += wb * bf16hi(db.y);
        }
    }
    s0 += __shfl_xor(s0, 16); s1 += __shfl_xor(s1, 16);
    s2 += __shfl_xor(s2, 16); s3 += __shfl_xor(s3, 16);
    s0 += __shfl_xor(s0, 32); s1 += __shfl_xor(s1, 32);
    s2 += __shfl_xor(s2, 32); s3 += __shfl_xor(s3, 32);
    if (lane < 16) {
        float4* ap = (float4*)(acc + (size_t)d * HD + l16 * 4);
        float4 a = *ap;
        a.x += s0; a.y += s1; a.z += s2; a.w += s3;
        *ap = a;
    }
}

// ---------------- finalize layer 1: relu(acc+b) -> bf16 hi/lo ----------------
__global__ void fin1_kernel(const float* __restrict__ acc, const float* __restrict__ bias,
                            unsigned short* __restrict__ hi, unsigned short* __restrict__ lo,
                            int NH) {
    int i = blockIdx.x * 256 + threadIdx.x;
    if (i < NH) {
        float v = fmaxf(acc[i] + bias[i & (HD - 1)], 0.f);
        unsigned short h = f32_to_bf16_rne(v);
        hi[i] = h;
        lo[i] = f32_to_bf16_rne(v - bf16_to_f32(h));
    }
}

// ---------------- mean pool, fused relu+bias: wave per 256 sorted nodes -------
__global__ __launch_bounds__(256) void pool_kernel(const float* __restrict__ acc,
                                                   const float* __restrict__ bias,
                                                   const int* __restrict__ batch,
                                                   float* __restrict__ pooled,
                                                   float* __restrict__ gcnt, int N) {
    int w = blockIdx.x * 4 + (threadIdx.x >> 6);
    int lane = threadIdx.x & 63;
    int base = w * 256;
    if (base >= N) return;
    float b = bias[lane];
    int cur = -1; float sum = 0.f; int cnt = 0;
    int end = min(base + 256, N);
    for (int n = base; n < end; ++n) {
        int g = batch[n];
        if (g != cur) {
            if (cur >= 0) {
                atomicAdd(&pooled[cur * HD + lane], sum);
                if (lane == 0) atomicAdd(&gcnt[cur], (float)cnt);
            }
            cur = g; sum = 0.f; cnt = 0;
        }
        sum += fmaxf(acc[(size_t)n * HD + lane] + b, 0.f);
        cnt++;
    }
    if (cur >= 0) {
        atomicAdd(&pooled[cur * HD + lane], sum);
        if (lane == 0) atomicAdd(&gcnt[cur], (float)cnt);
    }
}

__global__ void cls_kernel(const float* __restrict__ pooled, const float* __restrict__ gcnt,
                           const float* __restrict__ cls_w, const float* __restrict__ cls_b,
                           float* __restrict__ out) {
    int g = threadIdx.x;   // 64 graphs
    float invc = 1.0f / fmaxf(gcnt[g], 1.0f);
    float acc = 0.f;
    for (int j = 0; j < 64; ++j) acc += pooled[g * 64 + j] * cls_w[j];
    out[g] = acc * invc + cls_b[0];
}

extern "C" void kernel_launch(void* const* d_in, const int* in_sizes, int n_in,
                              void* d_out, int out_size, void* d_ws, size_t ws_size,
                              hipStream_t stream) {
    const float* x     = (const float*)d_in[0];
    const int*   eidx  = (const int*)d_in[1];
    const int*   et    = (const int*)d_in[2];
    const int*   batch = (const int*)d_in[3];
    const float* W1    = (const float*)d_in[4];
    const float* root1 = (const float*)d_in[5];
    const float* b1    = (const float*)d_in[6];
    const float* W2    = (const float*)d_in[7];
    const float* root2 = (const float*)d_in[8];
    const float* b2    = (const float*)d_in[9];
    const float* cls_w = (const float*)d_in[10];
    const float* cls_b = (const float*)d_in[11];

    const int N = in_sizes[3];
    const int E = in_sizes[2];
    const int NB = (N + 1023) / 1024;              // scan blocks over N
    const int NBK = (N + (1 << BSH) - 1) >> BSH;   // <=512 buckets
    const int* srcp = eidx;
    const int* dstp = eidx + E;

    char* ws = (char*)d_ws;
    size_t off = 0;
    auto alloc = [&](size_t bytes) -> void* {
        void* p = ws + off;
        off = (off + bytes + 255) & ~(size_t)255;
        return p;
    };
    // fixed buffers (~104 MB) + h_chunk 128 MB = ~232 MB total
    unsigned short* Xhi  = (unsigned short*)alloc((size_t)N * 128 * 2);   // 25.6 MB
    unsigned short* Xlo  = (unsigned short*)alloc((size_t)N * 128 * 2);   // 25.6 MB
    float*          accb = (float*)alloc((size_t)N * HD * 4);             // 25.6 MB
    unsigned short* Wt1hi = (unsigned short*)alloc((size_t)(R_REL + 1) * HD * 128 * 2);
    unsigned short* Wt1lo = (unsigned short*)alloc((size_t)(R_REL + 1) * HD * 128 * 2);
    unsigned short* Wt2hi = (unsigned short*)alloc((size_t)(R_REL + 1) * HD * HD * 2);
    unsigned short* Wt2lo = (unsigned short*)alloc((size_t)(R_REL + 1) * HD * HD * 2);
    int2*  edata  = (int2*)alloc((size_t)E * 8);                          // 25.6 MB
    int*   rowptr = (int*)alloc((size_t)(N + 1) * 4);
    int*   dcnt   = (int*)alloc((size_t)N * 4);
    int*   bsum   = (int*)alloc((size_t)NB * 4);
    int*   bofs   = (int*)alloc((size_t)NB * 4);
    int*   bcnt   = (int*)alloc(512 * 4);
    int*   bboff  = (int*)alloc(513 * 4);
    int*   gcur   = (int*)alloc(512 * 4);
    float* pooled = (float*)alloc((size_t)(64 * HD + 64) * 4);
    float* gcnt   = pooled + 64 * HD;
    unsigned short* h_chunk = (unsigned short*)alloc((size_t)R_REL * N * HD * 2);  // 128 MB

    // aliases (stream-ordered, safe):
    // staged (25.6 MB) over Xhi: consumed by sortfill before split writes Xhi.
    // H1hi/H1lo over Xhi/Xlo: written by fin1 AFTER the last gemm read of X.
    int2* staged = (int2*)Xhi;
    unsigned short* H1hi = Xhi;
    unsigned short* H1lo = Xlo;

    hipMemsetAsync(bcnt, 0, 512 * 4, stream);
    hipMemsetAsync(pooled, 0, (size_t)(64 * HD + 64) * 4, stream);

    // ---- bucketed CSR build: edata {rel*N+src, 1/cnt} + dst-level rowptr ----
    int nchunks = (E + 4095) / 4096;
    bhist_kernel<<<nchunks, 256, 0, stream>>>(dstp, bcnt, E);
    bscan_kernel<<<1, 512, 0, stream>>>(bcnt, bboff, gcur, NBK, E);
    bscatter_kernel<<<nchunks, 256, 0, stream>>>(srcp, dstp, et, gcur, staged, E);
    sortfill_kernel<<<NBK, 256, 0, stream>>>(staged, bboff, dcnt, edata, N, N);
    scan1_kernel<<<NB, 256, 0, stream>>>(dcnt, bsum, N);
    scan2_kernel<<<1, 1024, 0, stream>>>(bsum, bofs, NB);
    scan3_kernel<<<NB, 256, 0, stream>>>(dcnt, bofs, rowptr, N);

    // ---- precision-split operands (after staged is dead) ----
    int NK = N * 128;
    split_kernel<<<(NK + 255) / 256, 256, 0, stream>>>(x, Xhi, Xlo, NK);
    int tw1 = (R_REL + 1) * HD * 128, tw2 = (R_REL + 1) * HD * HD;
    wsplit_kernel<<<(tw1 + 255) / 256, 256, 0, stream>>>(W1, root1, Wt1hi, Wt1lo, 128);
    wsplit_kernel<<<(tw2 + 255) / 256, 256, 0, stream>>>(W2, root2, Wt2hi, Wt2lo, HD);

    const int gemmBlocks = (N + 63) / 64;
    const int aggBlocks  = (int)(((size_t)N * 64 + 255) / 256);
    const int NH = N * HD;

    // ---- layer 1 (K=128) ----
    gemm_mfma<128, true><<<gemmBlocks, 256, 0, stream>>>(Xhi, Xlo, Wt1hi, Wt1lo,
                                                         (unsigned short*)nullptr, accb,
                                                         R_REL, 1, N);   // accb = x @ root1
    gemm_mfma<128, false><<<gemmBlocks, 256, 0, stream>>>(Xhi, Xlo, Wt1hi, Wt1lo,
                                                          h_chunk, (float*)nullptr,
                                                          0, R_REL, N);
    agg_kernel<<<aggBlocks, 256, 0, stream>>>(h_chunk, rowptr, edata, accb, N);
    fin1_kernel<<<(NH + 255) / 256, 256, 0, stream>>>(accb, b1, H1hi, H1lo, NH);

    // ---- layer 2 (K=64) ----
    gemm_mfma<64, true><<<gemmBlocks, 256, 0, stream>>>(H1hi, H1lo, Wt2hi, Wt2lo,
                                                        (unsigned short*)nullptr, accb,
                                                        R_REL, 1, N);    // accb = h1 @ root2
    gemm_mfma<64, false><<<gemmBlocks, 256, 0, stream>>>(H1hi, H1lo, Wt2hi, Wt2lo,
                                                         h_chunk, (float*)nullptr,
                                                         0, R_REL, N);
    agg_kernel<<<aggBlocks, 256, 0, stream>>>(h_chunk, rowptr, edata, accb, N);

    // ---- pool (fused relu+bias) + classify ----
    int poolWaves = (N + 255) / 256;
    pool_kernel<<<(poolWaves + 3) / 4, 256, 0, stream>>>(accb, b2, batch, pooled, gcnt, N);
    cls_kernel<<<1, 64, 0, stream>>>(pooled, gcnt, cls_w, cls_b, (float*)d_out);
}